// Round 1
// baseline (4682.978 us; speedup 1.0000x reference)
//
#include <hip/hip_runtime.h>
#include <math.h>

// DiagonalLSTM: B=8, Cin=HID=128, H=64, W=64, K=2, T = 2W-1 = 127 steps.
//
// Round 0 design (correctness-first):
//   - transpose_x: x (B,C,H,W) -> xT (B,H,W,C) for vectorized z-loads (skipped
//     if ws too small; fallback reads x with scalar broadcast loads).
//   - 127x step_kernel launches; per launch, WG = (row-pair rg, unit-chunk q):
//     chunk = 16 hid units x 4 gates = 64 outputs; 256 threads = 64 outputs x
//     4-way K-split; weights cached in VGPRs (96 floats/thread); h rows staged
//     in LDS; K-partials reduced through LDS; gates + c/h update + out write.
//   - h double-buffered in ws; c updated in place (same thread owns the cell).
// Future rounds: persistent spin-sync wavefront kernel (same step body),
// f16/MFMA inner product, band-only scheduling.

#define HID 128
#define BB 8
#define HH 64
#define WW 64
#define TT 127

__global__ __launch_bounds__(256) void transpose_x(const float* __restrict__ x,
                                                   float* __restrict__ xT) {
  // x: (B, 128, H, W) -> xT: (B, H, W, 128)
  int b = blockIdx.x >> 6;
  int r = blockIdx.x & 63;
  __shared__ float tile[32][65];
  for (int cc = 0; cc < 4; cc++) {
    int cl = threadIdx.x >> 6;  // 0..3
    int w = threadIdx.x & 63;
#pragma unroll
    for (int k = 0; k < 8; k++) {
      int c_loc = k * 4 + cl;  // 0..31
      int c = cc * 32 + c_loc;
      tile[c_loc][w] = x[(((size_t)b * 128 + c) * HH + r) * WW + w];
    }
    __syncthreads();
    int cs = threadIdx.x & 31;
    int wp = threadIdx.x >> 5;  // 0..7
#pragma unroll
    for (int k = 0; k < 8; k++) {
      int w2 = wp * 8 + k;
      xT[(((size_t)b * HH + r) * WW + w2) * 128 + cc * 32 + cs] = tile[cs][w2];
    }
    __syncthreads();
  }
}

__global__ __launch_bounds__(256) void step_kernel(
    const float* __restrict__ x,   // (B,128,H,W) original layout
    const float* __restrict__ xT,  // (B,H,W,128) or nullptr
    int use_xT,
    const float* __restrict__ w_is,  // (512,128)
    const float* __restrict__ b_is,  // (512)
    const float* __restrict__ w_ss,  // (512,128,2,1) flat
    const float* __restrict__ b_ss,  // (512)
    const float* __restrict__ h_prev,  // (B,H,HID)
    float* __restrict__ h_next,        // (B,H,HID)
    float* __restrict__ c_state,       // (B,H,HID) in-place
    float* __restrict__ out,           // (B,HID,H,W)
    int t) {
  const int rg = blockIdx.x;  // 0..31 -> rows {2rg, 2rg+1}
  const int q = blockIdx.y;   // 0..7  -> hid units [16q, 16q+16)
  const int r0 = rg * 2;
  const int tid = threadIdx.x;
  const int o_loc = tid & 63;  // 64 chunk outputs: g*16+u
  const int k4 = tid >> 6;     // 4-way K split
  const int g_ = o_loc >> 4;
  const int u_ = o_loc & 15;
  const int O = g_ * 128 + q * 16 + u_;  // global output row in [0,512)
  const int i0 = k4 * 32;                // this thread's input range [i0, i0+32)

  __shared__ __align__(16) float h_in[3][BB][HID];  // rows r0-1, r0, r0+1
  __shared__ float zred[16][4][65];                 // [cell][k4][o_loc] padded

  // ---- stage h rows into LDS (coalesced over u) ----
  for (int idx = tid; idx < 3 * BB * HID; idx += 256) {
    int row_sel = idx >> 10;  // /1024
    int rem = idx & 1023;
    int b = rem >> 7;
    int u = rem & 127;
    int r = r0 - 1 + row_sel;
    h_in[row_sel][b][u] = (r >= 0) ? h_prev[((size_t)b * HH + r) * HID + u] : 0.0f;
  }

  // ---- weights into registers (must stay fully unrolled!) ----
  float wr0[32], wr1[32], wz[32];
  {
    const float4* wss4 = (const float4*)(w_ss + ((size_t)O * 128 + i0) * 2);
#pragma unroll
    for (int j = 0; j < 16; j++) {
      float4 v = wss4[j];  // w0[i], w1[i], w0[i+1], w1[i+1]
      wr0[2 * j] = v.x;
      wr1[2 * j] = v.y;
      wr0[2 * j + 1] = v.z;
      wr1[2 * j + 1] = v.w;
    }
    const float4* wis4 = (const float4*)(w_is + (size_t)O * 128 + i0);
#pragma unroll
    for (int j = 0; j < 8; j++) {
      float4 v = wis4[j];
      wz[4 * j] = v.x;
      wz[4 * j + 1] = v.y;
      wz[4 * j + 2] = v.z;
      wz[4 * j + 3] = v.w;
    }
  }

  __syncthreads();

  float acc[2][BB];
#pragma unroll
  for (int rl = 0; rl < 2; rl++)
#pragma unroll
    for (int b = 0; b < BB; b++) acc[rl][b] = 0.0f;

  // ---- recurrent part: wr0*h[r-1] + wr1*h[r] ----
#pragma unroll
  for (int jb = 0; jb < 8; jb++) {
    int ib = i0 + jb * 4;
#pragma unroll
    for (int b = 0; b < BB; b++) {
      const float4 hm4 = *(const float4*)&h_in[0][b][ib];
      const float4 hc4 = *(const float4*)&h_in[1][b][ib];
      const float4 hp4 = *(const float4*)&h_in[2][b][ib];
      const float* hm = (const float*)&hm4;
      const float* hc = (const float*)&hc4;
      const float* hp = (const float*)&hp4;
#pragma unroll
      for (int jj = 0; jj < 4; jj++) {
        float w0v = wr0[jb * 4 + jj];
        float w1v = wr1[jb * 4 + jj];
        acc[0][b] += w0v * hm[jj] + w1v * hc[jj];  // cell row r0
        acc[1][b] += w0v * hc[jj] + w1v * hp[jj];  // cell row r0+1
      }
    }
  }

  // ---- input-to-state part (in-band only): wz . x[b,:,r,t-r] ----
#pragma unroll
  for (int rl = 0; rl < 2; rl++) {
    int r = r0 + rl;
    int wcol = t - r;
    if (wcol >= 0 && wcol < WW) {
      if (use_xT) {
        for (int b = 0; b < BB; b++) {
          const float4* xp =
              (const float4*)(xT + (((size_t)b * HH + r) * WW + wcol) * 128 + i0);
#pragma unroll
          for (int j = 0; j < 8; j++) {
            float4 v = xp[j];
            acc[rl][b] += wz[4 * j] * v.x + wz[4 * j + 1] * v.y +
                          wz[4 * j + 2] * v.z + wz[4 * j + 3] * v.w;
          }
        }
      } else {
        for (int b = 0; b < BB; b++) {
          const float* xb = x + (((size_t)b * 128 + i0) * HH + r) * WW + wcol;
#pragma unroll
          for (int j = 0; j < 32; j++) {
            acc[rl][b] += wz[j] * xb[(size_t)j * HH * WW];
          }
        }
      }
    }
  }

  // ---- K-split reduction through LDS ----
#pragma unroll
  for (int rl = 0; rl < 2; rl++)
#pragma unroll
    for (int b = 0; b < BB; b++) zred[rl * 8 + b][k4][o_loc] = acc[rl][b];
  __syncthreads();

  // ---- gates: thread = (u in 16, cell in 16) ----
  {
    int u = tid >> 4;
    int cell = tid & 15;
    int rl = cell >> 3;
    int b = cell & 7;
    int r = r0 + rl;
    float z[4];
#pragma unroll
    for (int gg = 0; gg < 4; gg++) {
      int ol = gg * 16 + u;
      float s = zred[cell][0][ol] + zred[cell][1][ol] + zred[cell][2][ol] +
                zred[cell][3][ol];
      int Og = gg * 128 + q * 16 + u;
      z[gg] = s + b_is[Og] + b_ss[Og];
    }
    float iv = 1.0f / (1.0f + expf(-z[0]));
    float fv = 1.0f / (1.0f + expf(-z[1]));
    float ov = 1.0f / (1.0f + expf(-z[2]));
    float gv = tanhf(z[3]);
    int U = q * 16 + u;
    size_t sidx = ((size_t)b * HH + r) * HID + U;
    float cv = c_state[sidx];
    float cn = fv * cv + iv * gv;
    c_state[sidx] = cn;
    float hn = ov * tanhf(cn);
    h_next[sidx] = hn;
    int wcol = t - r;
    if (wcol >= 0 && wcol < WW) {
      out[(((size_t)b * HID + U) * HH + r) * WW + wcol] = hn;
    }
  }
}

extern "C" void kernel_launch(void* const* d_in, const int* in_sizes, int n_in,
                              void* d_out, int out_size, void* d_ws,
                              size_t ws_size, hipStream_t stream) {
  const float* x = (const float*)d_in[0];
  const float* w_is = (const float*)d_in[1];
  const float* b_is = (const float*)d_in[2];
  const float* w_ss = (const float*)d_in[3];
  const float* b_ss = (const float*)d_in[4];
  float* out = (float*)d_out;

  const size_t xT_elems = (size_t)BB * HH * WW * 128;  // 4,194,304
  const size_t st_elems = (size_t)BB * HH * HID;       // 65,536 per buffer
  const size_t need_xT = (xT_elems + 3 * st_elems) * sizeof(float);

  float* ws = (float*)d_ws;
  float* xT = nullptr;
  float* st;
  int use_xT = 0;
  if (ws_size >= need_xT) {
    use_xT = 1;
    xT = ws;
    st = ws + xT_elems;
  } else {
    st = ws;  // fallback: only state buffers (786 KB)
  }
  float* h0 = st;
  float* h1 = st + st_elems;
  float* cb = st + 2 * st_elems;

  // harness poisons ws with 0xAA before every launch -> must re-zero state
  hipMemsetAsync(st, 0, 3 * st_elems * sizeof(float), stream);
  if (use_xT) transpose_x<<<dim3(BB * HH), 256, 0, stream>>>(x, xT);

  for (int t = 0; t < TT; t++) {
    float* hp = (t & 1) ? h1 : h0;
    float* hn = (t & 1) ? h0 : h1;
    step_kernel<<<dim3(32, 8), 256, 0, stream>>>(x, xT, use_xT, w_is, b_is,
                                                 w_ss, b_ss, hp, hn, cb, out, t);
  }
}

// Round 3
// 4294.931 us; speedup vs baseline: 1.0904x; 1.0904x over previous
//
#include <hip/hip_runtime.h>
#include <hip/hip_fp16.h>
#include <math.h>

// DiagonalLSTM: B=8, Cin=HID=128, H=64, W=64, K=2, T = 2W-1 = 127 steps.
//
// Round 3 design:
//   - zpre_kernel: z_is (w/o bias) for all (b,r,w) as fp16, layout (B,H,W,512).
//   - lstm_persistent (NORMAL launch, 512 blocks x 256 thr, co-residency
//     guaranteed by resource arithmetic): per-step producer/consumer sync via
//     per-rg arrival counters (device-scope atomics + agent fences). h history
//     in fp16, one slot per step (no write-after-read hazards, arbitrary
//     inter-block skew allowed). c-state in registers. fp32 gate math.
//   - Fallback if ws < ~50.4 MB: round-1 127-launch path (proven correct).

#define HID 128
#define BB 8
#define HH 64
#define WW 64
#define TT 127

// ---------------- z_is precompute: (B,H,W,512) fp16 ----------------
__global__ __launch_bounds__(256) void zpre_kernel(const float* __restrict__ x,
                                                   const float* __restrict__ w_is,
                                                   __half* __restrict__ zph) {
  const int b = blockIdx.x >> 6;
  const int r = blockIdx.x & 63;
  const int tid = threadIdx.x;
  __shared__ __align__(16) float xt[64][132];  // [w][c]
  __shared__ __align__(16) float wt[32][132];  // [o][c] per 32-O chunk

#pragma unroll
  for (int i = 0; i < 8; i++) {
    int idx = tid + i * 256;  // 0..2047
    int c = idx >> 4;
    int w4 = idx & 15;
    float4 v = *(const float4*)&x[(((size_t)b * 128 + c) * HH + r) * WW + 4 * w4];
    xt[4 * w4 + 0][c] = v.x;
    xt[4 * w4 + 1][c] = v.y;
    xt[4 * w4 + 2][c] = v.z;
    xt[4 * w4 + 3][c] = v.w;
  }

  const int op = tid & 15;
  const int wp = tid >> 4;
  const size_t obase = ((size_t)b * HH + r) * WW;

  for (int oc = 0; oc < 16; oc++) {
    __syncthreads();
#pragma unroll
    for (int i = 0; i < 4; i++) {
      int idx = tid + i * 256;  // 0..1023
      int o = idx >> 5;
      int k4 = idx & 31;
      *(float4*)&wt[o][4 * k4] =
          *(const float4*)&w_is[((size_t)(oc * 32 + o)) * 128 + 4 * k4];
    }
    __syncthreads();
    float acc[4][2];
#pragma unroll
    for (int wi = 0; wi < 4; wi++)
#pragma unroll
      for (int oi = 0; oi < 2; oi++) acc[wi][oi] = 0.f;
#pragma unroll
    for (int kg = 0; kg < 32; kg++) {
      float4 xv[4], wv[2];
#pragma unroll
      for (int wi = 0; wi < 4; wi++) xv[wi] = *(float4*)&xt[wp + 16 * wi][4 * kg];
#pragma unroll
      for (int oi = 0; oi < 2; oi++) wv[oi] = *(float4*)&wt[op + 16 * oi][4 * kg];
#pragma unroll
      for (int wi = 0; wi < 4; wi++)
#pragma unroll
        for (int oi = 0; oi < 2; oi++) {
          acc[wi][oi] += xv[wi].x * wv[oi].x + xv[wi].y * wv[oi].y +
                         xv[wi].z * wv[oi].z + xv[wi].w * wv[oi].w;
        }
    }
#pragma unroll
    for (int wi = 0; wi < 4; wi++)
#pragma unroll
      for (int oi = 0; oi < 2; oi++) {
        zph[(obase + wp + 16 * wi) * 512 + oc * 32 + op + 16 * oi] =
            __float2half(acc[wi][oi]);
      }
  }
}

// ---------------- persistent recurrent kernel (normal launch) ----------------
// grid = 512 blocks: rg = id&31 (row pair), q = id>>5 in [0,16) (8-unit chunk)
// 256 threads = 32 outputs (4 gates x 8 units) x 8-way K-split.
__global__ __launch_bounds__(256, 2) void lstm_persistent(
    const __half* __restrict__ zph, const float* __restrict__ b_is,
    const float* __restrict__ w_ss, const float* __restrict__ b_ss,
    __half* __restrict__ hist,       // 128 slots x (B*H*HID) fp16; slot0 = 0
    unsigned* __restrict__ cnt,      // [TT][32] arrival counters, init 0
    float* __restrict__ out) {
  const int id = blockIdx.x;
  const int rg = id & 31;
  const int q = id >> 5;  // 0..15
  const int r0 = rg * 2;
  const int tid = threadIdx.x;
  const int o_loc = tid & 31;  // g*8+u
  const int k8 = tid >> 5;     // 0..7
  const int g_ = o_loc >> 3;
  const int u_ = o_loc & 7;
  const int O = g_ * 128 + q * 8 + u_;
  const int i0 = k8 * 16;

  // gate-phase mapping (first 128 threads)
  const int gu = tid & 7;
  const int gcell = tid >> 3;  // 0..15 for tid<128
  const int grl = gcell >> 3;
  const int gb = gcell & 7;
  const int gr = r0 + grl;
  const int gU = q * 8 + gu;

  __shared__ __align__(16) float h_in[3][BB][HID];  // rows r0-1..r0+1, fp32
  __shared__ float zred[16][8][33];

  // weights (k-slice) into registers, once
  float wr0[16], wr1[16];
  {
    const float4* wss4 = (const float4*)(w_ss + ((size_t)O * 128 + i0) * 2);
#pragma unroll
    for (int j = 0; j < 8; j++) {
      float4 v = wss4[j];  // w0[c], w1[c], w0[c+1], w1[c+1]
      wr0[2 * j] = v.x;
      wr1[2 * j] = v.y;
      wr0[2 * j + 1] = v.z;
      wr1[2 * j + 1] = v.w;
    }
  }
  float bsum[4];
#pragma unroll
  for (int gg = 0; gg < 4; gg++) {
    int Og = gg * 128 + gU;
    bsum[gg] = b_is[Og] + b_ss[Og];
  }

  float c_reg = 0.f;

  for (int t = 0; t < TT; t++) {
    // ---- z prefetch (step-independent of h) ----
    float zp4[4] = {0.f, 0.f, 0.f, 0.f};
    const int gw = t - gr;
    const bool inband = (gw >= 0) && (gw < WW) && (tid < 128);
    if (inband) {
      const __half* p = zph + (((size_t)gb * HH + gr) * WW + gw) * 512 + gU;
#pragma unroll
      for (int gg = 0; gg < 4; gg++) zp4[gg] = __half2float(p[gg * 128]);
    }

    // ---- wait for step t-1 producers of rows r0-1..r0+1 ----
    if (t > 0) {
      if (tid < 64) {  // one wave polls; fence below covers all waves
        const unsigned* c0 = &cnt[(size_t)(t - 1) * 32 + rg];
        const unsigned* c1 = (rg > 0) ? (c0 - 1) : c0;
        while (__hip_atomic_load(c0, __ATOMIC_RELAXED, __HIP_MEMORY_SCOPE_AGENT) < 16u ||
               __hip_atomic_load(c1, __ATOMIC_RELAXED, __HIP_MEMORY_SCOPE_AGENT) < 16u) {
          __builtin_amdgcn_s_sleep(2);
        }
      }
      __syncthreads();
      __builtin_amdgcn_fence(__ATOMIC_ACQUIRE, "agent");
    }

    // ---- stage h(t-1) rows into LDS as fp32 ----
    {
      const __half2* hsrc = (const __half2*)(hist + (size_t)t * (BB * HH * HID));
#pragma unroll
      for (int i = 0; i < 6; i++) {
        int idx = tid + i * 256;  // 0..1535 half2s
        int row_sel = idx >> 9;   // /512
        int rem = idx & 511;
        int bb2 = rem >> 6;
        int u2 = rem & 63;
        int rr = r0 - 1 + row_sel;
        float2 v = make_float2(0.f, 0.f);
        if (rr >= 0) v = __half22float2(hsrc[((size_t)bb2 * HH + rr) * 64 + u2]);
        *(float2*)&h_in[row_sel][bb2][2 * u2] = v;
      }
    }
    __syncthreads();

    // ---- recurrent dot: wr0*h[r-1] + wr1*h[r] ----
    float acc[2][BB];
#pragma unroll
    for (int rl = 0; rl < 2; rl++)
#pragma unroll
      for (int b = 0; b < BB; b++) acc[rl][b] = 0.f;
#pragma unroll
    for (int jb = 0; jb < 4; jb++) {
      int ib = i0 + jb * 4;
#pragma unroll
      for (int b = 0; b < BB; b++) {
        const float4 hm4 = *(const float4*)&h_in[0][b][ib];
        const float4 hc4 = *(const float4*)&h_in[1][b][ib];
        const float4 hp4 = *(const float4*)&h_in[2][b][ib];
        const float* hm = (const float*)&hm4;
        const float* hc = (const float*)&hc4;
        const float* hq = (const float*)&hp4;
#pragma unroll
        for (int jj = 0; jj < 4; jj++) {
          float w0v = wr0[jb * 4 + jj];
          float w1v = wr1[jb * 4 + jj];
          acc[0][b] += w0v * hm[jj] + w1v * hc[jj];
          acc[1][b] += w0v * hc[jj] + w1v * hq[jj];
        }
      }
    }

    // ---- K-split reduction through LDS ----
#pragma unroll
    for (int rl = 0; rl < 2; rl++)
#pragma unroll
      for (int b = 0; b < BB; b++) zred[rl * 8 + b][k8][o_loc] = acc[rl][b];
    __syncthreads();

    // ---- gates (128 threads) ----
    if (tid < 128) {
      float z[4];
#pragma unroll
      for (int gg = 0; gg < 4; gg++) {
        int ol = gg * 8 + gu;
        float s = 0.f;
#pragma unroll
        for (int k = 0; k < 8; k++) s += zred[gcell][k][ol];
        z[gg] = s + bsum[gg] + zp4[gg];
      }
      float iv = 1.0f / (1.0f + expf(-z[0]));
      float fv = 1.0f / (1.0f + expf(-z[1]));
      float ov = 1.0f / (1.0f + expf(-z[2]));
      float gv = tanhf(z[3]);
      c_reg = fv * c_reg + iv * gv;
      float hval = ov * tanhf(c_reg);
      hist[(size_t)(t + 1) * (BB * HH * HID) + ((size_t)gb * HH + gr) * HID + gU] =
          __float2half(hval);
      if (gw >= 0 && gw < WW) {
        out[(((size_t)gb * HID + gU) * HH + gr) * WW + gw] = hval;
      }
    }
    __syncthreads();  // hn stores drained (vmcnt) before release

    if (tid == 0) {
      __hip_atomic_fetch_add(&cnt[(size_t)t * 32 + rg], 1u, __ATOMIC_RELEASE,
                             __HIP_MEMORY_SCOPE_AGENT);
    }
  }
}

// ================= round-1 fallback path (proven correct) =================
__global__ __launch_bounds__(256) void transpose_x(const float* __restrict__ x,
                                                   float* __restrict__ xT) {
  int b = blockIdx.x >> 6;
  int r = blockIdx.x & 63;
  __shared__ float tile[32][65];
  for (int cc = 0; cc < 4; cc++) {
    int cl = threadIdx.x >> 6;
    int w = threadIdx.x & 63;
#pragma unroll
    for (int k = 0; k < 8; k++) {
      int c_loc = k * 4 + cl;
      int c = cc * 32 + c_loc;
      tile[c_loc][w] = x[(((size_t)b * 128 + c) * HH + r) * WW + w];
    }
    __syncthreads();
    int cs = threadIdx.x & 31;
    int wp = threadIdx.x >> 5;
#pragma unroll
    for (int k = 0; k < 8; k++) {
      int w2 = wp * 8 + k;
      xT[(((size_t)b * HH + r) * WW + w2) * 128 + cc * 32 + cs] = tile[cs][w2];
    }
    __syncthreads();
  }
}

__global__ __launch_bounds__(256) void step_kernel(
    const float* __restrict__ x, const float* __restrict__ xT, int use_xT,
    const float* __restrict__ w_is, const float* __restrict__ b_is,
    const float* __restrict__ w_ss, const float* __restrict__ b_ss,
    const float* __restrict__ h_prev, float* __restrict__ h_next,
    float* __restrict__ c_state, float* __restrict__ out, int t) {
  const int rg = blockIdx.x;
  const int q = blockIdx.y;
  const int r0 = rg * 2;
  const int tid = threadIdx.x;
  const int o_loc = tid & 63;
  const int k4 = tid >> 6;
  const int g_ = o_loc >> 4;
  const int u_ = o_loc & 15;
  const int O = g_ * 128 + q * 16 + u_;
  const int i0 = k4 * 32;

  __shared__ __align__(16) float h_in[3][BB][HID];
  __shared__ float zred[16][4][65];

  for (int idx = tid; idx < 3 * BB * HID; idx += 256) {
    int row_sel = idx >> 10;
    int rem = idx & 1023;
    int b = rem >> 7;
    int u = rem & 127;
    int r = r0 - 1 + row_sel;
    h_in[row_sel][b][u] = (r >= 0) ? h_prev[((size_t)b * HH + r) * HID + u] : 0.0f;
  }

  float wr0[32], wr1[32], wz[32];
  {
    const float4* wss4 = (const float4*)(w_ss + ((size_t)O * 128 + i0) * 2);
#pragma unroll
    for (int j = 0; j < 16; j++) {
      float4 v = wss4[j];
      wr0[2 * j] = v.x;
      wr1[2 * j] = v.y;
      wr0[2 * j + 1] = v.z;
      wr1[2 * j + 1] = v.w;
    }
    const float4* wis4 = (const float4*)(w_is + (size_t)O * 128 + i0);
#pragma unroll
    for (int j = 0; j < 8; j++) {
      float4 v = wis4[j];
      wz[4 * j] = v.x;
      wz[4 * j + 1] = v.y;
      wz[4 * j + 2] = v.z;
      wz[4 * j + 3] = v.w;
    }
  }

  __syncthreads();

  float acc[2][BB];
#pragma unroll
  for (int rl = 0; rl < 2; rl++)
#pragma unroll
    for (int b = 0; b < BB; b++) acc[rl][b] = 0.0f;

#pragma unroll
  for (int jb = 0; jb < 8; jb++) {
    int ib = i0 + jb * 4;
#pragma unroll
    for (int b = 0; b < BB; b++) {
      const float4 hm4 = *(const float4*)&h_in[0][b][ib];
      const float4 hc4 = *(const float4*)&h_in[1][b][ib];
      const float4 hp4 = *(const float4*)&h_in[2][b][ib];
      const float* hm = (const float*)&hm4;
      const float* hc = (const float*)&hc4;
      const float* hq = (const float*)&hp4;
#pragma unroll
      for (int jj = 0; jj < 4; jj++) {
        float w0v = wr0[jb * 4 + jj];
        float w1v = wr1[jb * 4 + jj];
        acc[0][b] += w0v * hm[jj] + w1v * hc[jj];
        acc[1][b] += w0v * hc[jj] + w1v * hq[jj];
      }
    }
  }

#pragma unroll
  for (int rl = 0; rl < 2; rl++) {
    int r = r0 + rl;
    int wcol = t - r;
    if (wcol >= 0 && wcol < WW) {
      if (use_xT) {
        for (int b = 0; b < BB; b++) {
          const float4* xp =
              (const float4*)(xT + (((size_t)b * HH + r) * WW + wcol) * 128 + i0);
#pragma unroll
          for (int j = 0; j < 8; j++) {
            float4 v = xp[j];
            acc[rl][b] += wz[4 * j] * v.x + wz[4 * j + 1] * v.y +
                          wz[4 * j + 2] * v.z + wz[4 * j + 3] * v.w;
          }
        }
      } else {
        for (int b = 0; b < BB; b++) {
          const float* xb = x + (((size_t)b * 128 + i0) * HH + r) * WW + wcol;
#pragma unroll
          for (int j = 0; j < 32; j++) {
            acc[rl][b] += wz[j] * xb[(size_t)j * HH * WW];
          }
        }
      }
    }
  }

#pragma unroll
  for (int rl = 0; rl < 2; rl++)
#pragma unroll
    for (int b = 0; b < BB; b++) zred[rl * 8 + b][k4][o_loc] = acc[rl][b];
  __syncthreads();

  {
    int u = tid >> 4;
    int cell = tid & 15;
    int rl = cell >> 3;
    int b = cell & 7;
    int r = r0 + rl;
    float z[4];
#pragma unroll
    for (int gg = 0; gg < 4; gg++) {
      int ol = gg * 16 + u;
      float s = zred[cell][0][ol] + zred[cell][1][ol] + zred[cell][2][ol] +
                zred[cell][3][ol];
      int Og = gg * 128 + q * 16 + u;
      z[gg] = s + b_is[Og] + b_ss[Og];
    }
    float iv = 1.0f / (1.0f + expf(-z[0]));
    float fv = 1.0f / (1.0f + expf(-z[1]));
    float ov = 1.0f / (1.0f + expf(-z[2]));
    float gv = tanhf(z[3]);
    int U = q * 16 + u;
    size_t sidx = ((size_t)b * HH + r) * HID + U;
    float cv = c_state[sidx];
    float cn = fv * cv + iv * gv;
    c_state[sidx] = cn;
    float hn = ov * tanhf(cn);
    h_next[sidx] = hn;
    int wcol = t - r;
    if (wcol >= 0 && wcol < WW) {
      out[(((size_t)b * HID + U) * HH + r) * WW + wcol] = hn;
    }
  }
}

extern "C" void kernel_launch(void* const* d_in, const int* in_sizes, int n_in,
                              void* d_out, int out_size, void* d_ws,
                              size_t ws_size, hipStream_t stream) {
  const float* x = (const float*)d_in[0];
  const float* w_is = (const float*)d_in[1];
  const float* b_is = (const float*)d_in[2];
  const float* w_ss = (const float*)d_in[3];
  const float* b_ss = (const float*)d_in[4];
  float* outp = (float*)d_out;

  const size_t zph_elems = (size_t)BB * HH * WW * 512;  // 16,777,216 halfs
  const size_t slot = (size_t)BB * HH * HID;            // 65,536 halfs/slot
  const size_t hist_elems = slot * 128;                 // 8,388,608 halfs
  const size_t cnt_elems = 128 * 32;                    // u32
  const size_t need =
      zph_elems * 2 + hist_elems * 2 + cnt_elems * sizeof(unsigned);

  char* ws = (char*)d_ws;
  if (ws_size >= need) {
    __half* zph = (__half*)ws;
    __half* hist = (__half*)(ws + zph_elems * 2);
    unsigned* cnt = (unsigned*)(ws + zph_elems * 2 + hist_elems * 2);
    // slot 0 (= h at t=-1) must be zeros; counters must start at 0
    hipMemsetAsync(hist, 0, slot * 2, stream);
    hipMemsetAsync(cnt, 0, cnt_elems * sizeof(unsigned), stream);
    zpre_kernel<<<dim3(BB * HH), 256, 0, stream>>>(x, w_is, zph);
    lstm_persistent<<<dim3(512), 256, 0, stream>>>(zph, b_is, w_ss, b_ss, hist,
                                                   cnt, outp);
  } else {
    // -------- round-1 fallback --------
    const size_t xT_elems = (size_t)BB * HH * WW * 128;
    const size_t st_elems = (size_t)BB * HH * HID;
    const size_t need_xT = (xT_elems + 3 * st_elems) * sizeof(float);
    float* wsf = (float*)d_ws;
    float* xT = nullptr;
    float* st;
    int use_xT = 0;
    if (ws_size >= need_xT) {
      use_xT = 1;
      xT = wsf;
      st = wsf + xT_elems;
    } else {
      st = wsf;
    }
    float* h0 = st;
    float* h1 = st + st_elems;
    float* cb = st + 2 * st_elems;
    hipMemsetAsync(st, 0, 3 * st_elems * sizeof(float), stream);
    if (use_xT) transpose_x<<<dim3(BB * HH), 256, 0, stream>>>(x, xT);
    for (int t = 0; t < TT; t++) {
      float* hp = (t & 1) ? h1 : h0;
      float* hn = (t & 1) ? h0 : h1;
      step_kernel<<<dim3(32, 8), 256, 0, stream>>>(x, xT, use_xT, w_is, b_is,
                                                   w_ss, b_ss, hp, hn, cb, outp,
                                                   t);
    }
  }
}

// Round 4
// 1305.204 us; speedup vs baseline: 3.5879x; 3.2906x over previous
//
#include <hip/hip_runtime.h>
#include <hip/hip_fp16.h>
#include <math.h>

// DiagonalLSTM: B=8, Cin=HID=128, H=64, W=64, K=2, T = 2W-1 = 127 steps.
//
// Round 4 design (round 3 minus agent-scope fences):
//   - All cross-block traffic (h history u32-packed fp16, arrival counters)
//     uses RELAXED agent-scope atomics -> cache-bypassing loads/stores at the
//     coherent point; NO acquire/release fences -> no buffer_inv/buffer_wbl2
//     (round 3's 33 us/step was ~128 L2 flush ops per XCD per step).
//   - Producer ordering: data stores -> s_waitcnt(0) (acks from coherent
//     point) -> __syncthreads -> relaxed flag add. Consumer: relaxed poll ->
//     __syncthreads -> relaxed data loads. Separate history slot per step
//     (no WAR hazards at any inter-block skew).
//   - zpre fp16 (B,H,W,512); recurrent weights in VGPRs; c-state in regs.
//   - Fallback if ws < ~50.4 MB: round-1 127-launch path (proven correct).

#define HID 128
#define BB 8
#define HH 64
#define WW 64
#define TT 127

// ---------------- z_is precompute: (B,H,W,512) fp16 ----------------
__global__ __launch_bounds__(256) void zpre_kernel(const float* __restrict__ x,
                                                   const float* __restrict__ w_is,
                                                   __half* __restrict__ zph) {
  const int b = blockIdx.x >> 6;
  const int r = blockIdx.x & 63;
  const int tid = threadIdx.x;
  __shared__ __align__(16) float xt[64][132];  // [w][c]
  __shared__ __align__(16) float wt[32][132];  // [o][c] per 32-O chunk

#pragma unroll
  for (int i = 0; i < 8; i++) {
    int idx = tid + i * 256;  // 0..2047
    int c = idx >> 4;
    int w4 = idx & 15;
    float4 v = *(const float4*)&x[(((size_t)b * 128 + c) * HH + r) * WW + 4 * w4];
    xt[4 * w4 + 0][c] = v.x;
    xt[4 * w4 + 1][c] = v.y;
    xt[4 * w4 + 2][c] = v.z;
    xt[4 * w4 + 3][c] = v.w;
  }

  const int op = tid & 15;
  const int wp = tid >> 4;
  const size_t obase = ((size_t)b * HH + r) * WW;

  for (int oc = 0; oc < 16; oc++) {
    __syncthreads();
#pragma unroll
    for (int i = 0; i < 4; i++) {
      int idx = tid + i * 256;  // 0..1023
      int o = idx >> 5;
      int k4 = idx & 31;
      *(float4*)&wt[o][4 * k4] =
          *(const float4*)&w_is[((size_t)(oc * 32 + o)) * 128 + 4 * k4];
    }
    __syncthreads();
    float acc[4][2];
#pragma unroll
    for (int wi = 0; wi < 4; wi++)
#pragma unroll
      for (int oi = 0; oi < 2; oi++) acc[wi][oi] = 0.f;
#pragma unroll
    for (int kg = 0; kg < 32; kg++) {
      float4 xv[4], wv[2];
#pragma unroll
      for (int wi = 0; wi < 4; wi++) xv[wi] = *(float4*)&xt[wp + 16 * wi][4 * kg];
#pragma unroll
      for (int oi = 0; oi < 2; oi++) wv[oi] = *(float4*)&wt[op + 16 * oi][4 * kg];
#pragma unroll
      for (int wi = 0; wi < 4; wi++)
#pragma unroll
        for (int oi = 0; oi < 2; oi++) {
          acc[wi][oi] += xv[wi].x * wv[oi].x + xv[wi].y * wv[oi].y +
                         xv[wi].z * wv[oi].z + xv[wi].w * wv[oi].w;
        }
    }
#pragma unroll
    for (int wi = 0; wi < 4; wi++)
#pragma unroll
      for (int oi = 0; oi < 2; oi++) {
        zph[(obase + wp + 16 * wi) * 512 + oc * 32 + op + 16 * oi] =
            __float2half(acc[wi][oi]);
      }
  }
}

// ---------------- persistent recurrent kernel (normal launch) ----------------
// grid = 512 blocks: rg = id&31 (row pair), q = id>>5 in [0,16) (8-unit chunk)
// 256 threads = 32 outputs (4 gates x 8 units) x 8-way K-split.
__global__ __launch_bounds__(256, 2) void lstm_persistent(
    const __half* __restrict__ zph, const float* __restrict__ b_is,
    const float* __restrict__ w_ss, const float* __restrict__ b_ss,
    __half* __restrict__ hist,   // 128 slots x (B*H*HID) fp16; slot0 = 0
    unsigned* __restrict__ cnt,  // [TT][32] arrival counters, init 0
    float* __restrict__ out) {
  const int id = blockIdx.x;
  const int rg = id & 31;
  const int q = id >> 5;  // 0..15
  const int r0 = rg * 2;
  const int tid = threadIdx.x;
  const int o_loc = tid & 31;  // g*8+u
  const int k8 = tid >> 5;     // 0..7
  const int g_ = o_loc >> 3;
  const int u_ = o_loc & 7;
  const int O = g_ * 128 + q * 8 + u_;
  const int i0 = k8 * 16;

  // gate-phase mapping (first 128 threads)
  const int gu = tid & 7;
  const int gcell = tid >> 3;  // 0..15 for tid<128
  const int grl = gcell >> 3;
  const int gb = gcell & 7;
  const int gr = r0 + grl;
  const int gU = q * 8 + gu;

  __shared__ __align__(16) float h_in[3][BB][HID];  // rows r0-1..r0+1, fp32
  __shared__ float zred[16][8][33];

  // weights (k-slice) into registers, once
  float wr0[16], wr1[16];
  {
    const float4* wss4 = (const float4*)(w_ss + ((size_t)O * 128 + i0) * 2);
#pragma unroll
    for (int j = 0; j < 8; j++) {
      float4 v = wss4[j];  // w0[c], w1[c], w0[c+1], w1[c+1]
      wr0[2 * j] = v.x;
      wr1[2 * j] = v.y;
      wr0[2 * j + 1] = v.z;
      wr1[2 * j + 1] = v.w;
    }
  }
  float bsum[4];
#pragma unroll
  for (int gg = 0; gg < 4; gg++) {
    int Og = gg * 128 + gU;
    bsum[gg] = b_is[Og] + b_ss[Og];
  }

  float c_reg = 0.f;

  for (int t = 0; t < TT; t++) {
    // ---- z prefetch (independent of h; zph is cached, written pre-kernel) ----
    float zp4[4] = {0.f, 0.f, 0.f, 0.f};
    const int gw = t - gr;
    const bool inband = (gw >= 0) && (gw < WW) && (tid < 128);
    if (inband) {
      const __half* p = zph + (((size_t)gb * HH + gr) * WW + gw) * 512 + gU;
#pragma unroll
      for (int gg = 0; gg < 4; gg++) zp4[gg] = __half2float(p[gg * 128]);
    }

    // ---- wait for step t-1 producers of rows r0-1..r0+1 (relaxed polls) ----
    if (t > 0) {
      if (tid < 64) {
        const unsigned* c0 = &cnt[(size_t)(t - 1) * 32 + rg];
        const unsigned* c1 = (rg > 0) ? (c0 - 1) : c0;
        while (__hip_atomic_load(c0, __ATOMIC_RELAXED,
                                 __HIP_MEMORY_SCOPE_AGENT) < 16u ||
               __hip_atomic_load(c1, __ATOMIC_RELAXED,
                                 __HIP_MEMORY_SCOPE_AGENT) < 16u) {
          __builtin_amdgcn_s_sleep(1);
        }
      }
      __syncthreads();  // no acquire fence: data went through coherent point
    }

    // ---- stage h(t-1) rows into LDS as fp32 (cache-bypassing u32 loads) ----
    {
      const unsigned* hsrc32 =
          (const unsigned*)hist + (size_t)t * (BB * HH * HID / 2);
#pragma unroll
      for (int i = 0; i < 6; i++) {
        int idx = tid + i * 256;  // 0..1535 u32s
        int row_sel = idx >> 9;   // /512
        int rem = idx & 511;
        int bb2 = rem >> 6;
        int u2 = rem & 63;
        int rr = r0 - 1 + row_sel;
        float2 v = make_float2(0.f, 0.f);
        if (rr >= 0) {
          unsigned raw = __hip_atomic_load(
              &hsrc32[((size_t)bb2 * HH + rr) * 64 + u2], __ATOMIC_RELAXED,
              __HIP_MEMORY_SCOPE_AGENT);
          v = __half22float2(*(__half2*)&raw);
        }
        *(float2*)&h_in[row_sel][bb2][2 * u2] = v;
      }
    }
    __syncthreads();

    // ---- recurrent dot: wr0*h[r-1] + wr1*h[r] ----
    float acc[2][BB];
#pragma unroll
    for (int rl = 0; rl < 2; rl++)
#pragma unroll
      for (int b = 0; b < BB; b++) acc[rl][b] = 0.f;
#pragma unroll
    for (int jb = 0; jb < 4; jb++) {
      int ib = i0 + jb * 4;
#pragma unroll
      for (int b = 0; b < BB; b++) {
        const float4 hm4 = *(const float4*)&h_in[0][b][ib];
        const float4 hc4 = *(const float4*)&h_in[1][b][ib];
        const float4 hp4 = *(const float4*)&h_in[2][b][ib];
        const float* hm = (const float*)&hm4;
        const float* hc = (const float*)&hc4;
        const float* hq = (const float*)&hp4;
#pragma unroll
        for (int jj = 0; jj < 4; jj++) {
          float w0v = wr0[jb * 4 + jj];
          float w1v = wr1[jb * 4 + jj];
          acc[0][b] += w0v * hm[jj] + w1v * hc[jj];
          acc[1][b] += w0v * hc[jj] + w1v * hq[jj];
        }
      }
    }

    // ---- K-split reduction through LDS ----
#pragma unroll
    for (int rl = 0; rl < 2; rl++)
#pragma unroll
      for (int b = 0; b < BB; b++) zred[rl * 8 + b][k8][o_loc] = acc[rl][b];
    __syncthreads();

    // ---- gates (128 threads) ----
    if (tid < 128) {
      float z[4];
#pragma unroll
      for (int gg = 0; gg < 4; gg++) {
        int ol = gg * 8 + gu;
        float s = 0.f;
#pragma unroll
        for (int k = 0; k < 8; k++) s += zred[gcell][k][ol];
        z[gg] = s + bsum[gg] + zp4[gg];
      }
      float iv = 1.0f / (1.0f + expf(-z[0]));
      float fv = 1.0f / (1.0f + expf(-z[1]));
      float ov = 1.0f / (1.0f + expf(-z[2]));
      float gv = tanhf(z[3]);
      c_reg = fv * c_reg + iv * gv;
      float hval = ov * tanhf(c_reg);
      // pack adjacent units into u32, cache-bypassing store to hist slot t+1
      float partner = __shfl_xor(hval, 1);
      if ((gu & 1) == 0) {
        __half2 h2;
        h2.x = __float2half(hval);
        h2.y = __float2half(partner);
        unsigned raw = *(unsigned*)&h2;
        unsigned* dst =
            (unsigned*)hist + (size_t)(t + 1) * (BB * HH * HID / 2) +
            (((size_t)gb * HH + gr) * HID + gU) / 2;
        __hip_atomic_store(dst, raw, __ATOMIC_RELAXED,
                           __HIP_MEMORY_SCOPE_AGENT);
      }
      if (gw >= 0 && gw < WW) {
        out[(((size_t)gb * HID + gU) * HH + gr) * WW + gw] = hval;
      }
    }

    // drain our stores (acks from coherent point), then announce
    __atomic_signal_fence(__ATOMIC_SEQ_CST);
    __builtin_amdgcn_s_waitcnt(0);
    __atomic_signal_fence(__ATOMIC_SEQ_CST);
    __syncthreads();
    if (tid == 0) {
      __hip_atomic_fetch_add(&cnt[(size_t)t * 32 + rg], 1u, __ATOMIC_RELAXED,
                             __HIP_MEMORY_SCOPE_AGENT);
    }
  }
}

// ================= round-1 fallback path (proven correct) =================
__global__ __launch_bounds__(256) void transpose_x(const float* __restrict__ x,
                                                   float* __restrict__ xT) {
  int b = blockIdx.x >> 6;
  int r = blockIdx.x & 63;
  __shared__ float tile[32][65];
  for (int cc = 0; cc < 4; cc++) {
    int cl = threadIdx.x >> 6;
    int w = threadIdx.x & 63;
#pragma unroll
    for (int k = 0; k < 8; k++) {
      int c_loc = k * 4 + cl;
      int c = cc * 32 + c_loc;
      tile[c_loc][w] = x[(((size_t)b * 128 + c) * HH + r) * WW + w];
    }
    __syncthreads();
    int cs = threadIdx.x & 31;
    int wp = threadIdx.x >> 5;
#pragma unroll
    for (int k = 0; k < 8; k++) {
      int w2 = wp * 8 + k;
      xT[(((size_t)b * HH + r) * WW + w2) * 128 + cc * 32 + cs] = tile[cs][w2];
    }
    __syncthreads();
  }
}

__global__ __launch_bounds__(256) void step_kernel(
    const float* __restrict__ x, const float* __restrict__ xT, int use_xT,
    const float* __restrict__ w_is, const float* __restrict__ b_is,
    const float* __restrict__ w_ss, const float* __restrict__ b_ss,
    const float* __restrict__ h_prev, float* __restrict__ h_next,
    float* __restrict__ c_state, float* __restrict__ out, int t) {
  const int rg = blockIdx.x;
  const int q = blockIdx.y;
  const int r0 = rg * 2;
  const int tid = threadIdx.x;
  const int o_loc = tid & 63;
  const int k4 = tid >> 6;
  const int g_ = o_loc >> 4;
  const int u_ = o_loc & 15;
  const int O = g_ * 128 + q * 16 + u_;
  const int i0 = k4 * 32;

  __shared__ __align__(16) float h_in[3][BB][HID];
  __shared__ float zred[16][4][65];

  for (int idx = tid; idx < 3 * BB * HID; idx += 256) {
    int row_sel = idx >> 10;
    int rem = idx & 1023;
    int b = rem >> 7;
    int u = rem & 127;
    int r = r0 - 1 + row_sel;
    h_in[row_sel][b][u] = (r >= 0) ? h_prev[((size_t)b * HH + r) * HID + u] : 0.0f;
  }

  float wr0[32], wr1[32], wz[32];
  {
    const float4* wss4 = (const float4*)(w_ss + ((size_t)O * 128 + i0) * 2);
#pragma unroll
    for (int j = 0; j < 16; j++) {
      float4 v = wss4[j];
      wr0[2 * j] = v.x;
      wr1[2 * j] = v.y;
      wr0[2 * j + 1] = v.z;
      wr1[2 * j + 1] = v.w;
    }
    const float4* wis4 = (const float4*)(w_is + (size_t)O * 128 + i0);
#pragma unroll
    for (int j = 0; j < 8; j++) {
      float4 v = wis4[j];
      wz[4 * j] = v.x;
      wz[4 * j + 1] = v.y;
      wz[4 * j + 2] = v.z;
      wz[4 * j + 3] = v.w;
    }
  }

  __syncthreads();

  float acc[2][BB];
#pragma unroll
  for (int rl = 0; rl < 2; rl++)
#pragma unroll
    for (int b = 0; b < BB; b++) acc[rl][b] = 0.0f;

#pragma unroll
  for (int jb = 0; jb < 8; jb++) {
    int ib = i0 + jb * 4;
#pragma unroll
    for (int b = 0; b < BB; b++) {
      const float4 hm4 = *(const float4*)&h_in[0][b][ib];
      const float4 hc4 = *(const float4*)&h_in[1][b][ib];
      const float4 hp4 = *(const float4*)&h_in[2][b][ib];
      const float* hm = (const float*)&hm4;
      const float* hc = (const float*)&hc4;
      const float* hq = (const float*)&hp4;
#pragma unroll
      for (int jj = 0; jj < 4; jj++) {
        float w0v = wr0[jb * 4 + jj];
        float w1v = wr1[jb * 4 + jj];
        acc[0][b] += w0v * hm[jj] + w1v * hc[jj];
        acc[1][b] += w0v * hc[jj] + w1v * hq[jj];
      }
    }
  }

#pragma unroll
  for (int rl = 0; rl < 2; rl++) {
    int r = r0 + rl;
    int wcol = t - r;
    if (wcol >= 0 && wcol < WW) {
      if (use_xT) {
        for (int b = 0; b < BB; b++) {
          const float4* xp =
              (const float4*)(xT + (((size_t)b * HH + r) * WW + wcol) * 128 + i0);
#pragma unroll
          for (int j = 0; j < 8; j++) {
            float4 v = xp[j];
            acc[rl][b] += wz[4 * j] * v.x + wz[4 * j + 1] * v.y +
                          wz[4 * j + 2] * v.z + wz[4 * j + 3] * v.w;
          }
        }
      } else {
        for (int b = 0; b < BB; b++) {
          const float* xb = x + (((size_t)b * 128 + i0) * HH + r) * WW + wcol;
#pragma unroll
          for (int j = 0; j < 32; j++) {
            acc[rl][b] += wz[j] * xb[(size_t)j * HH * WW];
          }
        }
      }
    }
  }

#pragma unroll
  for (int rl = 0; rl < 2; rl++)
#pragma unroll
    for (int b = 0; b < BB; b++) zred[rl * 8 + b][k4][o_loc] = acc[rl][b];
  __syncthreads();

  {
    int u = tid >> 4;
    int cell = tid & 15;
    int rl = cell >> 3;
    int b = cell & 7;
    int r = r0 + rl;
    float z[4];
#pragma unroll
    for (int gg = 0; gg < 4; gg++) {
      int ol = gg * 16 + u;
      float s = zred[cell][0][ol] + zred[cell][1][ol] + zred[cell][2][ol] +
                zred[cell][3][ol];
      int Og = gg * 128 + q * 16 + u;
      z[gg] = s + b_is[Og] + b_ss[Og];
    }
    float iv = 1.0f / (1.0f + expf(-z[0]));
    float fv = 1.0f / (1.0f + expf(-z[1]));
    float ov = 1.0f / (1.0f + expf(-z[2]));
    float gv = tanhf(z[3]);
    int U = q * 16 + u;
    size_t sidx = ((size_t)b * HH + r) * HID + U;
    float cv = c_state[sidx];
    float cn = fv * cv + iv * gv;
    c_state[sidx] = cn;
    float hn = ov * tanhf(cn);
    h_next[sidx] = hn;
    int wcol = t - r;
    if (wcol >= 0 && wcol < WW) {
      out[(((size_t)b * HID + U) * HH + r) * WW + wcol] = hn;
    }
  }
}

extern "C" void kernel_launch(void* const* d_in, const int* in_sizes, int n_in,
                              void* d_out, int out_size, void* d_ws,
                              size_t ws_size, hipStream_t stream) {
  const float* x = (const float*)d_in[0];
  const float* w_is = (const float*)d_in[1];
  const float* b_is = (const float*)d_in[2];
  const float* w_ss = (const float*)d_in[3];
  const float* b_ss = (const float*)d_in[4];
  float* outp = (float*)d_out;

  const size_t zph_elems = (size_t)BB * HH * WW * 512;  // 16,777,216 halfs
  const size_t slot = (size_t)BB * HH * HID;            // 65,536 halfs/slot
  const size_t hist_elems = slot * 128;                 // 8,388,608 halfs
  const size_t cnt_elems = 128 * 32;                    // u32
  const size_t need =
      zph_elems * 2 + hist_elems * 2 + cnt_elems * sizeof(unsigned);

  char* ws = (char*)d_ws;
  if (ws_size >= need) {
    __half* zph = (__half*)ws;
    __half* hist = (__half*)(ws + zph_elems * 2);
    unsigned* cnt = (unsigned*)(ws + zph_elems * 2 + hist_elems * 2);
    // slot 0 (= h at t=-1) must be zeros; counters must start at 0
    hipMemsetAsync(hist, 0, slot * 2, stream);
    hipMemsetAsync(cnt, 0, cnt_elems * sizeof(unsigned), stream);
    zpre_kernel<<<dim3(BB * HH), 256, 0, stream>>>(x, w_is, zph);
    lstm_persistent<<<dim3(512), 256, 0, stream>>>(zph, b_is, w_ss, b_ss, hist,
                                                   cnt, outp);
  } else {
    // -------- round-1 fallback --------
    const size_t xT_elems = (size_t)BB * HH * WW * 128;
    const size_t st_elems = (size_t)BB * HH * HID;
    const size_t need_xT = (xT_elems + 3 * st_elems) * sizeof(float);
    float* wsf = (float*)d_ws;
    float* xT = nullptr;
    float* st;
    int use_xT = 0;
    if (ws_size >= need_xT) {
      use_xT = 1;
      xT = wsf;
      st = wsf + xT_elems;
    } else {
      st = wsf;
    }
    float* h0 = st;
    float* h1 = st + st_elems;
    float* cb = st + 2 * st_elems;
    hipMemsetAsync(st, 0, 3 * st_elems * sizeof(float), stream);
    if (use_xT) transpose_x<<<dim3(BB * HH), 256, 0, stream>>>(x, xT);
    for (int t = 0; t < TT; t++) {
      float* hp = (t & 1) ? h1 : h0;
      float* hn = (t & 1) ? h0 : h1;
      step_kernel<<<dim3(32, 8), 256, 0, stream>>>(x, xT, use_xT, w_is, b_is,
                                                   w_ss, b_ss, hp, hn, cb, outp,
                                                   t);
    }
  }
}

// Round 5
// 641.187 us; speedup vs baseline: 7.3036x; 2.0356x over previous
//
#include <hip/hip_runtime.h>
#include <hip/hip_fp16.h>
#include <math.h>

// DiagonalLSTM: B=8, Cin=HID=128, H=64, W=64, K=2, T = 2W-1 = 127 steps.
//
// Round 5 design (MFMA + minimal-surface sync):
//   - 32 persistent blocks = 8 row-groups (8 rows) x 4 batch-groups (2 b),
//     512 threads (8 waves), 1 block/CU guaranteed (<=256 VGPR via
//     __launch_bounds__(512,2)) -> co-residency by arithmetic.
//   - Recurrent GEMM per step: M=512, N=16 cells, K=256 via
//     mfma_f32_16x16x32_f16. Weights live in VGPRs (128/lane) in A-fragment
//     order (prep_w kernel, one-time). h(t-1) in LDS f16 (9 rows x 2 b).
//   - Gate-aligned tiling: wave w owns Mtiles {8g+w} -> all 4 gates of a
//     (cell,u) land in one lane; gates fully in-register; c in registers.
//   - Cross-block: ONLY the row-group boundary row (2x128 f16 = 512B/step),
//     single producer -> single consumer, relaxed uncached stores + plain
//     store flag (no RMW), unique slot per step (no WAR at any skew).
//   - zpre fp16 (B,H,W,512) as before; fallback = round-1 path if ws small.

#define HID 128
#define BB 8
#define HH 64
#define WW 64
#define TT 127

typedef _Float16 v8h __attribute__((ext_vector_type(8)));
typedef float v4f __attribute__((ext_vector_type(4)));

// ---------------- z_is precompute: (B,H,W,512) fp16 ----------------
__global__ __launch_bounds__(256) void zpre_kernel(const float* __restrict__ x,
                                                   const float* __restrict__ w_is,
                                                   __half* __restrict__ zph) {
  const int b = blockIdx.x >> 6;
  const int r = blockIdx.x & 63;
  const int tid = threadIdx.x;
  __shared__ __align__(16) float xt[64][132];  // [w][c]
  __shared__ __align__(16) float wt[32][132];  // [o][c] per 32-O chunk

#pragma unroll
  for (int i = 0; i < 8; i++) {
    int idx = tid + i * 256;  // 0..2047
    int c = idx >> 4;
    int w4 = idx & 15;
    float4 v = *(const float4*)&x[(((size_t)b * 128 + c) * HH + r) * WW + 4 * w4];
    xt[4 * w4 + 0][c] = v.x;
    xt[4 * w4 + 1][c] = v.y;
    xt[4 * w4 + 2][c] = v.z;
    xt[4 * w4 + 3][c] = v.w;
  }

  const int op = tid & 15;
  const int wp = tid >> 4;
  const size_t obase = ((size_t)b * HH + r) * WW;

  for (int oc = 0; oc < 16; oc++) {
    __syncthreads();
#pragma unroll
    for (int i = 0; i < 4; i++) {
      int idx = tid + i * 256;  // 0..1023
      int o = idx >> 5;
      int k4 = idx & 31;
      *(float4*)&wt[o][4 * k4] =
          *(const float4*)&w_is[((size_t)(oc * 32 + o)) * 128 + 4 * k4];
    }
    __syncthreads();
    float acc[4][2];
#pragma unroll
    for (int wi = 0; wi < 4; wi++)
#pragma unroll
      for (int oi = 0; oi < 2; oi++) acc[wi][oi] = 0.f;
#pragma unroll
    for (int kg = 0; kg < 32; kg++) {
      float4 xv[4], wv[2];
#pragma unroll
      for (int wi = 0; wi < 4; wi++) xv[wi] = *(float4*)&xt[wp + 16 * wi][4 * kg];
#pragma unroll
      for (int oi = 0; oi < 2; oi++) wv[oi] = *(float4*)&wt[op + 16 * oi][4 * kg];
#pragma unroll
      for (int wi = 0; wi < 4; wi++)
#pragma unroll
        for (int oi = 0; oi < 2; oi++) {
          acc[wi][oi] += xv[wi].x * wv[oi].x + xv[wi].y * wv[oi].y +
                         xv[wi].z * wv[oi].z + xv[wi].w * wv[oi].w;
        }
    }
#pragma unroll
    for (int wi = 0; wi < 4; wi++)
#pragma unroll
      for (int oi = 0; oi < 2; oi++) {
        zph[(obase + wp + 16 * wi) * 512 + oc * 32 + op + 16 * oi] =
            __float2half(acc[wi][oi]);
      }
  }
}

// ---------------- weight prep: Wcat(512x256) fp32 -> f16 A-fragments --------
// layout: wp[(((mt*8+kt)*64 + lane)*8 + j)] = Wcat[mt*16+(lane&15)]
//                                                 [kt*32+((lane>>4)&3)*8+j]
// Wcat[O][k] = k<128 ? w_ss[O][k][0] : w_ss[O][k-128][1]
__global__ __launch_bounds__(256) void prep_w(const float* __restrict__ w_ss,
                                              _Float16* __restrict__ wp) {
  int i = blockIdx.x * 256 + threadIdx.x;  // 0..131071
  int j = i & 7;
  int L = (i >> 3) & 63;
  int kt = (i >> 9) & 7;
  int mt = i >> 12;  // 0..31
  int O = mt * 16 + (L & 15);
  int k = kt * 32 + ((L >> 4) & 3) * 8 + j;
  float v = (k < 128) ? w_ss[(size_t)O * 256 + k * 2]
                      : w_ss[(size_t)O * 256 + (k - 128) * 2 + 1];
  wp[i] = (_Float16)v;
}

// ---------------- persistent MFMA recurrent kernel ----------------
#define HROW 136  // padded row stride in halfs (per (slot,b) row)

__global__ __launch_bounds__(512, 2) void lstm_mfma(
    const __half* __restrict__ zph, const _Float16* __restrict__ wp,
    const float* __restrict__ b_is, const float* __restrict__ b_ss,
    unsigned long long* __restrict__ hx,  // [TT][8][4][64] 8B-packed boundary
    unsigned* __restrict__ flags,         // [TT][32], init 0
    float* __restrict__ out) {
  const int blk = blockIdx.x;  // 0..31
  const int rgr = blk >> 2;    // row group 0..7 (rows 8*rgr .. +7)
  const int bg = blk & 3;      // batch group 0..3 (b = 2*bg, 2*bg+1)
  const int R0 = rgr * 8;
  const int tid = threadIdx.x;
  const int wv = tid >> 6;  // wave 0..7
  const int L = tid & 63;
  const int quad = L >> 4;
  const int l15 = L & 15;
  const int rl = l15 >> 1;  // cell row-local 0..7
  const int bl = l15 & 1;   // cell batch-local 0..1
  const int b = bg * 2 + bl;
  const int r = R0 + rl;
  const int uq0 = 16 * wv + quad * 4;  // D-side unit base (+reg)

  // h slots: slot s holds row R0-1+s (s=0..8), per b-local, 128 units + pad
  __shared__ _Float16 h_lds[9 * 2 * HROW];

  for (int i = tid; i < (9 * 2 * HROW) / 2; i += 512) ((unsigned*)h_lds)[i] = 0u;

  // ---- weights into VGPRs as A-fragments, once (128 VGPR/lane) ----
  v8h wfrag[4][8];
  {
    const v8h* wp8 = (const v8h*)wp;
#pragma unroll
    for (int g = 0; g < 4; g++)
#pragma unroll
      for (int kt = 0; kt < 8; kt++)
        wfrag[g][kt] = wp8[((size_t)((8 * g + wv) * 8 + kt)) * 64 + L];
  }

  float bsum[4][4];
#pragma unroll
  for (int g = 0; g < 4; g++)
#pragma unroll
    for (int rg2 = 0; rg2 < 4; rg2++) {
      int O = g * 128 + uq0 + rg2;
      bsum[g][rg2] = b_is[O] + b_ss[O];
    }

  float c[4] = {0.f, 0.f, 0.f, 0.f};

  const int ebl = L >> 5;        // boundary-exchange: b-local
  const int eu = (L & 31) * 4;   // boundary-exchange: unit base (4 halfs/lane)

  __syncthreads();

  for (int t = 0; t < TT; t++) {
    // ---- zp prefetch (4 halfs per gate, reg 0..3 consecutive) ----
    const int gw = t - r;
    const bool inband = (gw >= 0) && (gw < WW);
    uint2 zraw[4] = {{0u, 0u}, {0u, 0u}, {0u, 0u}, {0u, 0u}};
    if (inband) {
      const uint2* zp2 =
          (const uint2*)(zph + (((size_t)b * HH + r) * WW + gw) * 512 + uq0);
#pragma unroll
      for (int g = 0; g < 4; g++) zraw[g] = zp2[g * 32];  // stride 128 halfs
    }

    // ---- wave0: fetch neighbor boundary row h(t-1)[R0-1] into slot 0 ----
    if (wv == 0 && t > 0 && rgr > 0) {
      const unsigned* fl = &flags[(size_t)(t - 1) * 32 + (rgr - 1) * 4 + bg];
      while (__hip_atomic_load(fl, __ATOMIC_RELAXED,
                               __HIP_MEMORY_SCOPE_AGENT) == 0u) {
        __builtin_amdgcn_s_sleep(1);
      }
      unsigned long long v = __hip_atomic_load(
          &hx[(((size_t)(t - 1) * 8 + (rgr - 1)) * 4 + bg) * 64 + L],
          __ATOMIC_RELAXED, __HIP_MEMORY_SCOPE_AGENT);
      *(unsigned long long*)&h_lds[(0 * 2 + ebl) * HROW + eu] = v;
    }

    v4f acc[4];
#pragma unroll
    for (int g = 0; g < 4; g++) acc[g] = (v4f){0.f, 0.f, 0.f, 0.f};

    // ---- phase A: kt 4..7 (k>=128 -> own rows, slots 1..8) ----
#pragma unroll
    for (int kt = 4; kt < 8; kt++) {
      v8h bf = *(const v8h*)&h_lds[((rl + 1) * 2 + bl) * HROW +
                                   (kt - 4) * 32 + quad * 8];
#pragma unroll
      for (int g = 0; g < 4; g++)
        acc[g] = __builtin_amdgcn_mfma_f32_16x16x32_f16(wfrag[g][kt], bf,
                                                        acc[g], 0, 0, 0);
    }
    __syncthreads();  // boundary row in LDS

    // ---- phase B: kt 0..3 (k<128 -> rows r-1, slots 0..7) ----
#pragma unroll
    for (int kt = 0; kt < 4; kt++) {
      v8h bf =
          *(const v8h*)&h_lds[(rl * 2 + bl) * HROW + kt * 32 + quad * 8];
#pragma unroll
      for (int g = 0; g < 4; g++)
        acc[g] = __builtin_amdgcn_mfma_f32_16x16x32_f16(wfrag[g][kt], bf,
                                                        acc[g], 0, 0, 0);
    }
    __syncthreads();  // all LDS reads of h(t-1) complete

    // ---- gates (pure in-register; lane owns cell l15, units uq0..uq0+3) ----
    float hv[4];
#pragma unroll
    for (int rg2 = 0; rg2 < 4; rg2++) {
      float z[4];
#pragma unroll
      for (int g = 0; g < 4; g++) {
        union {
          unsigned u;
          __half2 h2;
        } cv;
        cv.u = (rg2 & 2) ? zraw[g].y : zraw[g].x;
        float2 f2 = __half22float2(cv.h2);
        float zp = (rg2 & 1) ? f2.y : f2.x;
        z[g] = acc[g][rg2] + bsum[g][rg2] + zp;
      }
      float iv = 1.f / (1.f + expf(-z[0]));
      float fv = 1.f / (1.f + expf(-z[1]));
      float ov = 1.f / (1.f + expf(-z[2]));
      float gv = tanhf(z[3]);
      c[rg2] = fv * c[rg2] + iv * gv;
      hv[rg2] = ov * tanhf(c[rg2]);
      if (inband) {
        out[(((size_t)b * HID + uq0 + rg2) * HH + r) * WW + gw] = hv[rg2];
      }
    }
    // h(t) -> LDS slots 1..8 (4 halfs per lane, 8B write)
    {
      __half2 lo = __floats2half2_rn(hv[0], hv[1]);
      __half2 hi = __floats2half2_rn(hv[2], hv[3]);
      uint2 pk;
      pk.x = *(unsigned*)&lo;
      pk.y = *(unsigned*)&hi;
      *(uint2*)&h_lds[((rl + 1) * 2 + bl) * HROW + uq0] = pk;
    }
    __syncthreads();  // h(t) complete in LDS

    // ---- wave1: export boundary row (slot 8 = row R0+7) + flag ----
    if (wv == 1 && rgr < 7) {
      unsigned long long v =
          *(const unsigned long long*)&h_lds[(8 * 2 + ebl) * HROW + eu];
      __hip_atomic_store(&hx[(((size_t)t * 8 + rgr) * 4 + bg) * 64 + L], v,
                         __ATOMIC_RELAXED, __HIP_MEMORY_SCOPE_AGENT);
      __builtin_amdgcn_s_waitcnt(0);  // data acked at coherent point
      if (L == 0) {
        __hip_atomic_store(&flags[(size_t)t * 32 + rgr * 4 + bg], 1u,
                           __ATOMIC_RELAXED, __HIP_MEMORY_SCOPE_AGENT);
      }
    }
  }
}

// ================= round-1 fallback path (proven correct) =================
__global__ __launch_bounds__(256) void transpose_x(const float* __restrict__ x,
                                                   float* __restrict__ xT) {
  int b = blockIdx.x >> 6;
  int r = blockIdx.x & 63;
  __shared__ float tile[32][65];
  for (int cc = 0; cc < 4; cc++) {
    int cl = threadIdx.x >> 6;
    int w = threadIdx.x & 63;
#pragma unroll
    for (int k = 0; k < 8; k++) {
      int c_loc = k * 4 + cl;
      int c = cc * 32 + c_loc;
      tile[c_loc][w] = x[(((size_t)b * 128 + c) * HH + r) * WW + w];
    }
    __syncthreads();
    int cs = threadIdx.x & 31;
    int wp = threadIdx.x >> 5;
#pragma unroll
    for (int k = 0; k < 8; k++) {
      int w2 = wp * 8 + k;
      xT[(((size_t)b * HH + r) * WW + w2) * 128 + cc * 32 + cs] = tile[cs][w2];
    }
    __syncthreads();
  }
}

__global__ __launch_bounds__(256) void step_kernel(
    const float* __restrict__ x, const float* __restrict__ xT, int use_xT,
    const float* __restrict__ w_is, const float* __restrict__ b_is,
    const float* __restrict__ w_ss, const float* __restrict__ b_ss,
    const float* __restrict__ h_prev, float* __restrict__ h_next,
    float* __restrict__ c_state, float* __restrict__ out, int t) {
  const int rg = blockIdx.x;
  const int q = blockIdx.y;
  const int r0 = rg * 2;
  const int tid = threadIdx.x;
  const int o_loc = tid & 63;
  const int k4 = tid >> 6;
  const int g_ = o_loc >> 4;
  const int u_ = o_loc & 15;
  const int O = g_ * 128 + q * 16 + u_;
  const int i0 = k4 * 32;

  __shared__ __align__(16) float h_in[3][BB][HID];
  __shared__ float zred[16][4][65];

  for (int idx = tid; idx < 3 * BB * HID; idx += 256) {
    int row_sel = idx >> 10;
    int rem = idx & 1023;
    int b = rem >> 7;
    int u = rem & 127;
    int rr = r0 - 1 + row_sel;
    h_in[row_sel][b][u] = (rr >= 0) ? h_prev[((size_t)b * HH + rr) * HID + u] : 0.0f;
  }

  float wr0[32], wr1[32], wz[32];
  {
    const float4* wss4 = (const float4*)(w_ss + ((size_t)O * 128 + i0) * 2);
#pragma unroll
    for (int j = 0; j < 16; j++) {
      float4 v = wss4[j];
      wr0[2 * j] = v.x;
      wr1[2 * j] = v.y;
      wr0[2 * j + 1] = v.z;
      wr1[2 * j + 1] = v.w;
    }
    const float4* wis4 = (const float4*)(w_is + (size_t)O * 128 + i0);
#pragma unroll
    for (int j = 0; j < 8; j++) {
      float4 v = wis4[j];
      wz[4 * j] = v.x;
      wz[4 * j + 1] = v.y;
      wz[4 * j + 2] = v.z;
      wz[4 * j + 3] = v.w;
    }
  }

  __syncthreads();

  float acc[2][BB];
#pragma unroll
  for (int rl = 0; rl < 2; rl++)
#pragma unroll
    for (int b = 0; b < BB; b++) acc[rl][b] = 0.0f;

#pragma unroll
  for (int jb = 0; jb < 8; jb++) {
    int ib = i0 + jb * 4;
#pragma unroll
    for (int b = 0; b < BB; b++) {
      const float4 hm4 = *(const float4*)&h_in[0][b][ib];
      const float4 hc4 = *(const float4*)&h_in[1][b][ib];
      const float4 hp4 = *(const float4*)&h_in[2][b][ib];
      const float* hm = (const float*)&hm4;
      const float* hc = (const float*)&hc4;
      const float* hq = (const float*)&hp4;
#pragma unroll
      for (int jj = 0; jj < 4; jj++) {
        float w0v = wr0[jb * 4 + jj];
        float w1v = wr1[jb * 4 + jj];
        acc[0][b] += w0v * hm[jj] + w1v * hc[jj];
        acc[1][b] += w0v * hc[jj] + w1v * hq[jj];
      }
    }
  }

#pragma unroll
  for (int rl = 0; rl < 2; rl++) {
    int rr = r0 + rl;
    int wcol = t - rr;
    if (wcol >= 0 && wcol < WW) {
      if (use_xT) {
        for (int b = 0; b < BB; b++) {
          const float4* xp =
              (const float4*)(xT + (((size_t)b * HH + rr) * WW + wcol) * 128 + i0);
#pragma unroll
          for (int j = 0; j < 8; j++) {
            float4 v = xp[j];
            acc[rl][b] += wz[4 * j] * v.x + wz[4 * j + 1] * v.y +
                          wz[4 * j + 2] * v.z + wz[4 * j + 3] * v.w;
          }
        }
      } else {
        for (int b = 0; b < BB; b++) {
          const float* xb = x + (((size_t)b * 128 + i0) * HH + rr) * WW + wcol;
#pragma unroll
          for (int j = 0; j < 32; j++) {
            acc[rl][b] += wz[j] * xb[(size_t)j * HH * WW];
          }
        }
      }
    }
  }

#pragma unroll
  for (int rl = 0; rl < 2; rl++)
#pragma unroll
    for (int b = 0; b < BB; b++) zred[rl * 8 + b][k4][o_loc] = acc[rl][b];
  __syncthreads();

  {
    int u = tid >> 4;
    int cell = tid & 15;
    int rl = cell >> 3;
    int b = cell & 7;
    int rr = r0 + rl;
    float z[4];
#pragma unroll
    for (int gg = 0; gg < 4; gg++) {
      int ol = gg * 16 + u;
      float s = zred[cell][0][ol] + zred[cell][1][ol] + zred[cell][2][ol] +
                zred[cell][3][ol];
      int Og = gg * 128 + q * 16 + u;
      z[gg] = s + b_is[Og] + b_ss[Og];
    }
    float iv = 1.0f / (1.0f + expf(-z[0]));
    float fv = 1.0f / (1.0f + expf(-z[1]));
    float ov = 1.0f / (1.0f + expf(-z[2]));
    float gv = tanhf(z[3]);
    int U = q * 16 + u;
    size_t sidx = ((size_t)b * HH + rr) * HID + U;
    float cv = c_state[sidx];
    float cn = fv * cv + iv * gv;
    c_state[sidx] = cn;
    float hn = ov * tanhf(cn);
    h_next[sidx] = hn;
    int wcol = t - rr;
    if (wcol >= 0 && wcol < WW) {
      out[(((size_t)b * HID + U) * HH + rr) * WW + wcol] = hn;
    }
  }
}

extern "C" void kernel_launch(void* const* d_in, const int* in_sizes, int n_in,
                              void* d_out, int out_size, void* d_ws,
                              size_t ws_size, hipStream_t stream) {
  const float* x = (const float*)d_in[0];
  const float* w_is = (const float*)d_in[1];
  const float* b_is = (const float*)d_in[2];
  const float* w_ss = (const float*)d_in[3];
  const float* b_ss = (const float*)d_in[4];
  float* outp = (float*)d_out;

  const size_t zph_bytes = (size_t)BB * HH * WW * 512 * 2;  // 32 MiB
  const size_t wp_bytes = (size_t)512 * 256 * 2;            // 256 KiB
  const size_t hx_bytes = (size_t)TT * 8 * 4 * 64 * 8;      // ~2.03 MiB
  const size_t fl_bytes = (size_t)TT * 32 * 4;              // ~16 KiB
  const size_t need = zph_bytes + wp_bytes + hx_bytes + fl_bytes;

  char* ws = (char*)d_ws;
  if (ws_size >= need) {
    __half* zph = (__half*)ws;
    _Float16* wpp = (_Float16*)(ws + zph_bytes);
    unsigned long long* hx = (unsigned long long*)(ws + zph_bytes + wp_bytes);
    unsigned* flags = (unsigned*)(ws + zph_bytes + wp_bytes + hx_bytes);

    hipMemsetAsync(flags, 0, fl_bytes, stream);
    zpre_kernel<<<dim3(BB * HH), 256, 0, stream>>>(x, w_is, zph);
    prep_w<<<dim3(512), 256, 0, stream>>>(w_ss, wpp);
    lstm_mfma<<<dim3(32), 512, 0, stream>>>(zph, wpp, b_is, b_ss, hx, flags,
                                            outp);
  } else {
    // -------- round-1 fallback --------
    const size_t xT_elems = (size_t)BB * HH * WW * 128;
    const size_t st_elems = (size_t)BB * HH * HID;
    const size_t need_xT = (xT_elems + 3 * st_elems) * sizeof(float);
    float* wsf = (float*)d_ws;
    float* xT = nullptr;
    float* st;
    int use_xT = 0;
    if (ws_size >= need_xT) {
      use_xT = 1;
      xT = wsf;
      st = wsf + xT_elems;
    } else {
      st = wsf;
    }
    float* h0 = st;
    float* h1 = st + st_elems;
    float* cb = st + 2 * st_elems;
    hipMemsetAsync(st, 0, 3 * st_elems * sizeof(float), stream);
    if (use_xT) transpose_x<<<dim3(BB * HH), 256, 0, stream>>>(x, xT);
    for (int t = 0; t < TT; t++) {
      float* hp = (t & 1) ? h1 : h0;
      float* hn = (t & 1) ? h0 : h1;
      step_kernel<<<dim3(32, 8), 256, 0, stream>>>(x, xT, use_xT, w_is, b_is,
                                                   w_ss, b_ss, hp, hn, cb, outp,
                                                   t);
    }
  }
}

// Round 6
// 607.003 us; speedup vs baseline: 7.7149x; 1.0563x over previous
//
#include <hip/hip_runtime.h>
#include <hip/hip_fp16.h>
#include <math.h>

// DiagonalLSTM: B=8, Cin=HID=128, H=64, W=64, K=2, T = 2W-1 = 127 steps.
//
// Round 6 design (round 5 + VALU/drain cuts):
//   - fast sigmoid/tanh via v_exp2+v_rcp (clamped) -> ~5x fewer gate VALU ops
//   - zpre layout (B,H,W)[u*4+g] -> lane's 16 gate halfs are 32B contiguous
//   - boundary export BEFORE out stores, s_waitcnt vmcnt-only (0x0f70)
//   - double-buffered h in LDS -> 2 syncthreads/step; incremental out addr
//   - otherwise round-5 structure: 32 blocks (8 rgr x 4 bg) x 512 thr, weights
//     as MFMA A-fragments in regs, boundary row exchange via uncached atomics.

#define HID 128
#define BB 8
#define HH 64
#define WW 64
#define TT 127

typedef _Float16 v8h __attribute__((ext_vector_type(8)));
typedef float v4f __attribute__((ext_vector_type(4)));

__device__ __forceinline__ float fsig(float x) {
  x = __builtin_fmaxf(__builtin_fminf(x, 30.f), -30.f);
  float e = __builtin_amdgcn_exp2f(x * -1.44269504f);
  return __builtin_amdgcn_rcpf(1.f + e);
}
__device__ __forceinline__ float ftanh_(float x) {
  x = __builtin_fmaxf(__builtin_fminf(x, 15.f), -15.f);
  float e = __builtin_amdgcn_exp2f(x * 2.88539009f);
  return (e - 1.f) * __builtin_amdgcn_rcpf(e + 1.f);
}

// -------- z_is precompute: (B,H,W)[u*4+g] fp16 (gate-interleaved) --------
__global__ __launch_bounds__(256) void zpre_kernel(const float* __restrict__ x,
                                                   const float* __restrict__ w_is,
                                                   __half* __restrict__ zph) {
  const int b = blockIdx.x >> 6;
  const int r = blockIdx.x & 63;
  const int tid = threadIdx.x;
  __shared__ __align__(16) float xt[64][132];  // [w][c]
  __shared__ __align__(16) float wt[32][132];  // [o][c] per 32-O chunk

#pragma unroll
  for (int i = 0; i < 8; i++) {
    int idx = tid + i * 256;  // 0..2047
    int c = idx >> 4;
    int w4 = idx & 15;
    float4 v = *(const float4*)&x[(((size_t)b * 128 + c) * HH + r) * WW + 4 * w4];
    xt[4 * w4 + 0][c] = v.x;
    xt[4 * w4 + 1][c] = v.y;
    xt[4 * w4 + 2][c] = v.z;
    xt[4 * w4 + 3][c] = v.w;
  }

  const int op = tid & 15;
  const int wp = tid >> 4;
  const size_t obase = ((size_t)b * HH + r) * WW;

  for (int oc = 0; oc < 16; oc++) {
    __syncthreads();
#pragma unroll
    for (int i = 0; i < 4; i++) {
      int idx = tid + i * 256;  // 0..1023
      int o = idx >> 5;
      int k4 = idx & 31;
      *(float4*)&wt[o][4 * k4] =
          *(const float4*)&w_is[((size_t)(oc * 32 + o)) * 128 + 4 * k4];
    }
    __syncthreads();
    float acc[4][2];
#pragma unroll
    for (int wi = 0; wi < 4; wi++)
#pragma unroll
      for (int oi = 0; oi < 2; oi++) acc[wi][oi] = 0.f;
#pragma unroll
    for (int kg = 0; kg < 32; kg++) {
      float4 xv[4], wv[2];
#pragma unroll
      for (int wi = 0; wi < 4; wi++) xv[wi] = *(float4*)&xt[wp + 16 * wi][4 * kg];
#pragma unroll
      for (int oi = 0; oi < 2; oi++) wv[oi] = *(float4*)&wt[op + 16 * oi][4 * kg];
#pragma unroll
      for (int wi = 0; wi < 4; wi++)
#pragma unroll
        for (int oi = 0; oi < 2; oi++) {
          acc[wi][oi] += xv[wi].x * wv[oi].x + xv[wi].y * wv[oi].y +
                         xv[wi].z * wv[oi].z + xv[wi].w * wv[oi].w;
        }
    }
#pragma unroll
    for (int wi = 0; wi < 4; wi++)
#pragma unroll
      for (int oi = 0; oi < 2; oi++) {
        int O = oc * 32 + op + 16 * oi;
        int u = O & 127;
        int g = O >> 7;
        zph[(obase + wp + 16 * wi) * 512 + u * 4 + g] = __float2half(acc[wi][oi]);
      }
  }
}

// ---------------- weight prep: Wcat(512x256) fp32 -> f16 A-fragments --------
__global__ __launch_bounds__(256) void prep_w(const float* __restrict__ w_ss,
                                              _Float16* __restrict__ wp) {
  int i = blockIdx.x * 256 + threadIdx.x;  // 0..131071
  int j = i & 7;
  int L = (i >> 3) & 63;
  int kt = (i >> 9) & 7;
  int mt = i >> 12;  // 0..31
  int O = mt * 16 + (L & 15);
  int k = kt * 32 + ((L >> 4) & 3) * 8 + j;
  float v = (k < 128) ? w_ss[(size_t)O * 256 + k * 2]
                      : w_ss[(size_t)O * 256 + (k - 128) * 2 + 1];
  wp[i] = (_Float16)v;
}

// ---------------- persistent MFMA recurrent kernel ----------------
#define HROW 136  // padded row stride in halfs

__global__ __launch_bounds__(512, 2) void lstm_mfma(
    const __half* __restrict__ zph, const _Float16* __restrict__ wp,
    const float* __restrict__ b_is, const float* __restrict__ b_ss,
    unsigned long long* __restrict__ hx,  // [TT][8][4][64] boundary rows
    unsigned* __restrict__ flags,         // [TT][32], init 0
    float* __restrict__ out) {
  const int blk = blockIdx.x;  // 0..31
  const int rgr = blk >> 2;    // row group 0..7 (rows 8*rgr .. +7)
  const int bg = blk & 3;      // batch group 0..3 (b = 2*bg, 2*bg+1)
  const int R0 = rgr * 8;
  const int tid = threadIdx.x;
  const int wv = tid >> 6;  // wave 0..7
  const int L = tid & 63;
  const int quad = L >> 4;
  const int l15 = L & 15;
  const int rl = l15 >> 1;  // cell row-local 0..7
  const int bl = l15 & 1;   // cell batch-local 0..1
  const int b = bg * 2 + bl;
  const int r = R0 + rl;
  const int uq0 = 16 * wv + quad * 4;  // D-side unit base (+reg)

  // double-buffered: slot s holds row R0-1+s (s=0..8), per b-local
  __shared__ _Float16 h_lds[2][9 * 2 * HROW];

  for (int i = tid; i < (2 * 9 * 2 * HROW) / 2; i += 512)
    ((unsigned*)h_lds)[i] = 0u;

  // ---- weights into regs as A-fragments, once (128 VGPR/lane) ----
  v8h wfrag[4][8];
  {
    const v8h* wp8 = (const v8h*)wp;
#pragma unroll
    for (int g = 0; g < 4; g++)
#pragma unroll
      for (int kt = 0; kt < 8; kt++)
        wfrag[g][kt] = wp8[((size_t)((8 * g + wv) * 8 + kt)) * 64 + L];
  }

  float bsum[4][4];
#pragma unroll
  for (int g = 0; g < 4; g++)
#pragma unroll
    for (int rg2 = 0; rg2 < 4; rg2++) {
      int O = g * 128 + uq0 + rg2;
      bsum[g][rg2] = b_is[O] + b_ss[O];
    }

  float c[4] = {0.f, 0.f, 0.f, 0.f};

  const int ebl = L >> 5;       // boundary-exchange: b-local
  const int eu = (L & 31) * 4;  // boundary-exchange: unit base (4 halfs/lane)

  // incremental out addressing: index = ob0 + rg2*4096 + t while inband
  const size_t ob0 = (((size_t)b * HID + uq0) * HH + r) * WW - (size_t)r;

  __syncthreads();

  for (int t = 0; t < TT; t++) {
    const int rb = t & 1;        // read buffer (holds h(t-1))
    const int wb = (t + 1) & 1;  // write buffer (h(t))

    // ---- zp prefetch: 16 contiguous halfs = 2x dwordx4 ----
    const int gw = t - r;
    const bool inband = (gw >= 0) && (gw < WW);
    union {
      uint4 q[2];
      __half h[16];
    } zu;
    zu.q[0] = (uint4){0u, 0u, 0u, 0u};
    zu.q[1] = (uint4){0u, 0u, 0u, 0u};
    if (inband) {
      const uint4* p =
          (const uint4*)(zph + (((size_t)b * HH + r) * WW + gw) * 512 + uq0 * 4);
      zu.q[0] = p[0];
      zu.q[1] = p[1];
    }

    // ---- wave0: fetch neighbor boundary row h(t-1)[R0-1] into rb slot 0 ----
    if (wv == 0 && t > 0 && rgr > 0) {
      const unsigned* fl = &flags[(size_t)(t - 1) * 32 + (rgr - 1) * 4 + bg];
      while (__hip_atomic_load(fl, __ATOMIC_RELAXED,
                               __HIP_MEMORY_SCOPE_AGENT) == 0u) {
        __builtin_amdgcn_s_sleep(1);
      }
      unsigned long long v = __hip_atomic_load(
          &hx[(((size_t)(t - 1) * 8 + (rgr - 1)) * 4 + bg) * 64 + L],
          __ATOMIC_RELAXED, __HIP_MEMORY_SCOPE_AGENT);
      *(unsigned long long*)&h_lds[rb][(0 * 2 + ebl) * HROW + eu] = v;
    }

    v4f acc[4];
#pragma unroll
    for (int g = 0; g < 4; g++) acc[g] = (v4f){0.f, 0.f, 0.f, 0.f};

    // ---- phase A: kt 4..7 (k>=128 -> own rows, slots 1..8) ----
#pragma unroll
    for (int kt = 4; kt < 8; kt++) {
      v8h bf = *(const v8h*)&h_lds[rb][((rl + 1) * 2 + bl) * HROW +
                                       (kt - 4) * 32 + quad * 8];
#pragma unroll
      for (int g = 0; g < 4; g++)
        acc[g] = __builtin_amdgcn_mfma_f32_16x16x32_f16(wfrag[g][kt], bf,
                                                        acc[g], 0, 0, 0);
    }
    __syncthreads();  // slot 0 (boundary) visible

    // ---- phase B: kt 0..3 (k<128 -> rows r-1, slots 0..7) ----
#pragma unroll
    for (int kt = 0; kt < 4; kt++) {
      v8h bf =
          *(const v8h*)&h_lds[rb][(rl * 2 + bl) * HROW + kt * 32 + quad * 8];
#pragma unroll
      for (int g = 0; g < 4; g++)
        acc[g] = __builtin_amdgcn_mfma_f32_16x16x32_f16(wfrag[g][kt], bf,
                                                        acc[g], 0, 0, 0);
    }

    // ---- gates (in-register; lane owns cell l15, units uq0..uq0+3) ----
    float hv[4];
#pragma unroll
    for (int rg2 = 0; rg2 < 4; rg2++) {
      float z[4];
#pragma unroll
      for (int g = 0; g < 4; g++) {
        z[g] = acc[g][rg2] + bsum[g][rg2] + __half2float(zu.h[rg2 * 4 + g]);
      }
      float iv = fsig(z[0]);
      float fv = fsig(z[1]);
      float ov = fsig(z[2]);
      float gv = ftanh_(z[3]);
      c[rg2] = fv * c[rg2] + iv * gv;
      hv[rg2] = ov * ftanh_(c[rg2]);
    }
    // h(t) -> write buffer slots 1..8 (4 halfs per lane, 8B write)
    {
      __half2 lo = __floats2half2_rn(hv[0], hv[1]);
      __half2 hi = __floats2half2_rn(hv[2], hv[3]);
      uint2 pk;
      pk.x = *(unsigned*)&lo;
      pk.y = *(unsigned*)&hi;
      *(uint2*)&h_lds[wb][((rl + 1) * 2 + bl) * HROW + uq0] = pk;
    }
    __syncthreads();  // h(t) complete in wb

    // ---- wave1: export boundary row (wb slot 8 = row R0+7) + flag ----
    if (wv == 1 && rgr < 7) {
      unsigned long long v =
          *(const unsigned long long*)&h_lds[wb][(8 * 2 + ebl) * HROW + eu];
      __hip_atomic_store(&hx[(((size_t)t * 8 + rgr) * 4 + bg) * 64 + L], v,
                         __ATOMIC_RELAXED, __HIP_MEMORY_SCOPE_AGENT);
      __builtin_amdgcn_s_waitcnt(0x0f70);  // vmcnt(0) only: hx acked
      if (L == 0) {
        __hip_atomic_store(&flags[(size_t)t * 32 + rgr * 4 + bg], 1u,
                           __ATOMIC_RELAXED, __HIP_MEMORY_SCOPE_AGENT);
      }
    }

    // ---- out stores AFTER export (drain in background) ----
    if (inband) {
#pragma unroll
      for (int rg2 = 0; rg2 < 4; rg2++) {
        out[ob0 + (size_t)rg2 * (HH * WW) + t] = hv[rg2];
      }
    }
  }
}

// ================= round-1 fallback path (proven correct) =================
__global__ __launch_bounds__(256) void transpose_x(const float* __restrict__ x,
                                                   float* __restrict__ xT) {
  int b = blockIdx.x >> 6;
  int r = blockIdx.x & 63;
  __shared__ float tile[32][65];
  for (int cc = 0; cc < 4; cc++) {
    int cl = threadIdx.x >> 6;
    int w = threadIdx.x & 63;
#pragma unroll
    for (int k = 0; k < 8; k++) {
      int c_loc = k * 4 + cl;
      int c = cc * 32 + c_loc;
      tile[c_loc][w] = x[(((size_t)b * 128 + c) * HH + r) * WW + w];
    }
    __syncthreads();
    int cs = threadIdx.x & 31;
    int wp = threadIdx.x >> 5;
#pragma unroll
    for (int k = 0; k < 8; k++) {
      int w2 = wp * 8 + k;
      xT[(((size_t)b * HH + r) * WW + w2) * 128 + cc * 32 + cs] = tile[cs][w2];
    }
    __syncthreads();
  }
}

__global__ __launch_bounds__(256) void step_kernel(
    const float* __restrict__ x, const float* __restrict__ xT, int use_xT,
    const float* __restrict__ w_is, const float* __restrict__ b_is,
    const float* __restrict__ w_ss, const float* __restrict__ b_ss,
    const float* __restrict__ h_prev, float* __restrict__ h_next,
    float* __restrict__ c_state, float* __restrict__ out, int t) {
  const int rg = blockIdx.x;
  const int q = blockIdx.y;
  const int r0 = rg * 2;
  const int tid = threadIdx.x;
  const int o_loc = tid & 63;
  const int k4 = tid >> 6;
  const int g_ = o_loc >> 4;
  const int u_ = o_loc & 15;
  const int O = g_ * 128 + q * 16 + u_;
  const int i0 = k4 * 32;

  __shared__ __align__(16) float h_in[3][BB][HID];
  __shared__ float zred[16][4][65];

  for (int idx = tid; idx < 3 * BB * HID; idx += 256) {
    int row_sel = idx >> 10;
    int rem = idx & 1023;
    int b = rem >> 7;
    int u = rem & 127;
    int rr = r0 - 1 + row_sel;
    h_in[row_sel][b][u] = (rr >= 0) ? h_prev[((size_t)b * HH + rr) * HID + u] : 0.0f;
  }

  float wr0[32], wr1[32], wz[32];
  {
    const float4* wss4 = (const float4*)(w_ss + ((size_t)O * 128 + i0) * 2);
#pragma unroll
    for (int j = 0; j < 16; j++) {
      float4 v = wss4[j];
      wr0[2 * j] = v.x;
      wr1[2 * j] = v.y;
      wr0[2 * j + 1] = v.z;
      wr1[2 * j + 1] = v.w;
    }
    const float4* wis4 = (const float4*)(w_is + (size_t)O * 128 + i0);
#pragma unroll
    for (int j = 0; j < 8; j++) {
      float4 v = wis4[j];
      wz[4 * j] = v.x;
      wz[4 * j + 1] = v.y;
      wz[4 * j + 2] = v.z;
      wz[4 * j + 3] = v.w;
    }
  }

  __syncthreads();

  float acc[2][BB];
#pragma unroll
  for (int rl = 0; rl < 2; rl++)
#pragma unroll
    for (int b = 0; b < BB; b++) acc[rl][b] = 0.0f;

#pragma unroll
  for (int jb = 0; jb < 8; jb++) {
    int ib = i0 + jb * 4;
#pragma unroll
    for (int b = 0; b < BB; b++) {
      const float4 hm4 = *(const float4*)&h_in[0][b][ib];
      const float4 hc4 = *(const float4*)&h_in[1][b][ib];
      const float4 hp4 = *(const float4*)&h_in[2][b][ib];
      const float* hm = (const float*)&hm4;
      const float* hc = (const float*)&hc4;
      const float* hq = (const float*)&hp4;
#pragma unroll
      for (int jj = 0; jj < 4; jj++) {
        float w0v = wr0[jb * 4 + jj];
        float w1v = wr1[jb * 4 + jj];
        acc[0][b] += w0v * hm[jj] + w1v * hc[jj];
        acc[1][b] += w0v * hc[jj] + w1v * hq[jj];
      }
    }
  }

#pragma unroll
  for (int rl = 0; rl < 2; rl++) {
    int rr = r0 + rl;
    int wcol = t - rr;
    if (wcol >= 0 && wcol < WW) {
      if (use_xT) {
        for (int b = 0; b < BB; b++) {
          const float4* xp =
              (const float4*)(xT + (((size_t)b * HH + rr) * WW + wcol) * 128 + i0);
#pragma unroll
          for (int j = 0; j < 8; j++) {
            float4 v = xp[j];
            acc[rl][b] += wz[4 * j] * v.x + wz[4 * j + 1] * v.y +
                          wz[4 * j + 2] * v.z + wz[4 * j + 3] * v.w;
          }
        }
      } else {
        for (int b = 0; b < BB; b++) {
          const float* xb = x + (((size_t)b * 128 + i0) * HH + rr) * WW + wcol;
#pragma unroll
          for (int j = 0; j < 32; j++) {
            acc[rl][b] += wz[j] * xb[(size_t)j * HH * WW];
          }
        }
      }
    }
  }

#pragma unroll
  for (int rl = 0; rl < 2; rl++)
#pragma unroll
    for (int b = 0; b < BB; b++) zred[rl * 8 + b][k4][o_loc] = acc[rl][b];
  __syncthreads();

  {
    int u = tid >> 4;
    int cell = tid & 15;
    int rl = cell >> 3;
    int b = cell & 7;
    int rr = r0 + rl;
    float z[4];
#pragma unroll
    for (int gg = 0; gg < 4; gg++) {
      int ol = gg * 16 + u;
      float s = zred[cell][0][ol] + zred[cell][1][ol] + zred[cell][2][ol] +
                zred[cell][3][ol];
      int Og = gg * 128 + q * 16 + u;
      z[gg] = s + b_is[Og] + b_ss[Og];
    }
    float iv = 1.0f / (1.0f + expf(-z[0]));
    float fv = 1.0f / (1.0f + expf(-z[1]));
    float ov = 1.0f / (1.0f + expf(-z[2]));
    float gv = tanhf(z[3]);
    int U = q * 16 + u;
    size_t sidx = ((size_t)b * HH + rr) * HID + U;
    float cv = c_state[sidx];
    float cn = fv * cv + iv * gv;
    c_state[sidx] = cn;
    float hn = ov * tanhf(cn);
    h_next[sidx] = hn;
    int wcol = t - rr;
    if (wcol >= 0 && wcol < WW) {
      out[(((size_t)b * HID + U) * HH + rr) * WW + wcol] = hn;
    }
  }
}

extern "C" void kernel_launch(void* const* d_in, const int* in_sizes, int n_in,
                              void* d_out, int out_size, void* d_ws,
                              size_t ws_size, hipStream_t stream) {
  const float* x = (const float*)d_in[0];
  const float* w_is = (const float*)d_in[1];
  const float* b_is = (const float*)d_in[2];
  const float* w_ss = (const float*)d_in[3];
  const float* b_ss = (const float*)d_in[4];
  float* outp = (float*)d_out;

  const size_t zph_bytes = (size_t)BB * HH * WW * 512 * 2;  // 32 MiB
  const size_t wp_bytes = (size_t)512 * 256 * 2;            // 256 KiB
  const size_t hx_bytes = (size_t)TT * 8 * 4 * 64 * 8;      // ~2.03 MiB
  const size_t fl_bytes = (size_t)TT * 32 * 4;              // ~16 KiB
  const size_t need = zph_bytes + wp_bytes + hx_bytes + fl_bytes;

  char* ws = (char*)d_ws;
  if (ws_size >= need) {
    __half* zph = (__half*)ws;
    _Float16* wpp = (_Float16*)(ws + zph_bytes);
    unsigned long long* hx = (unsigned long long*)(ws + zph_bytes + wp_bytes);
    unsigned* flags = (unsigned*)(ws + zph_bytes + wp_bytes + hx_bytes);

    hipMemsetAsync(flags, 0, fl_bytes, stream);
    zpre_kernel<<<dim3(BB * HH), 256, 0, stream>>>(x, w_is, zph);
    prep_w<<<dim3(512), 256, 0, stream>>>(w_ss, wpp);
    lstm_mfma<<<dim3(32), 512, 0, stream>>>(zph, wpp, b_is, b_ss, hx, flags,
                                            outp);
  } else {
    // -------- round-1 fallback --------
    const size_t xT_elems = (size_t)BB * HH * WW * 128;
    const size_t st_elems = (size_t)BB * HH * HID;
    const size_t need_xT = (xT_elems + 3 * st_elems) * sizeof(float);
    float* wsf = (float*)d_ws;
    float* xT = nullptr;
    float* st;
    int use_xT = 0;
    if (ws_size >= need_xT) {
      use_xT = 1;
      xT = wsf;
      st = wsf + xT_elems;
    } else {
      st = wsf;
    }
    float* h0 = st;
    float* h1 = st + st_elems;
    float* cb = st + 2 * st_elems;
    hipMemsetAsync(st, 0, 3 * st_elems * sizeof(float), stream);
    if (use_xT) transpose_x<<<dim3(BB * HH), 256, 0, stream>>>(x, xT);
    for (int t = 0; t < TT; t++) {
      float* hp = (t & 1) ? h1 : h0;
      float* hn = (t & 1) ? h0 : h1;
      step_kernel<<<dim3(32, 8), 256, 0, stream>>>(x, xT, use_xT, w_is, b_is,
                                                   w_ss, b_ss, hp, hn, cb, outp,
                                                   t);
    }
  }
}

// Round 7
// 428.552 us; speedup vs baseline: 10.9274x; 1.4164x over previous
//
#include <hip/hip_runtime.h>
#include <hip/hip_fp16.h>
#include <math.h>

// DiagonalLSTM: B=8, Cin=HID=128, H=64, W=64, K=2, T = 2W-1 = 127 steps.
//
// Round 7 design (round 6 with all latencies pipelined off the critical path):
//   - single barrier/step; boundary row prefetched 1 step ahead by wave0
//     (poll at step top, overlapped with MFMA; skew between row-groups absorbs
//     fabric latency -- strict one-way rgr DAG, no deadlock possible)
//   - lazy flags: export h(t)[R0+7] stored at t (direct from registers, lanes
//     l15>=14), flagged at t+1 after a then-free vmcnt(0) drain
//   - zp (z_is) prefetched 1 step ahead into registers
//   - out stores buffered in a float4 shift-window, flushed coalesced (16B)
//     every 4 steps per cell
//   - 32 blocks (8 rgr x 4 bg) x 512 thr, weights as MFMA A-fragments in
//     VGPRs (128/lane), c-state in registers, launch_bounds(512,1)

#define HID 128
#define BB 8
#define HH 64
#define WW 64
#define TT 127

typedef _Float16 v8h __attribute__((ext_vector_type(8)));
typedef float v4f __attribute__((ext_vector_type(4)));

__device__ __forceinline__ float fsig(float x) {
  x = __builtin_fmaxf(__builtin_fminf(x, 30.f), -30.f);
  float e = __builtin_amdgcn_exp2f(x * -1.44269504f);
  return __builtin_amdgcn_rcpf(1.f + e);
}
__device__ __forceinline__ float ftanh_(float x) {
  x = __builtin_fmaxf(__builtin_fminf(x, 15.f), -15.f);
  float e = __builtin_amdgcn_exp2f(x * 2.88539009f);
  return (e - 1.f) * __builtin_amdgcn_rcpf(e + 1.f);
}

// -------- z_is precompute: (B,H,W)[u*4+g] fp16 (gate-interleaved) --------
__global__ __launch_bounds__(256) void zpre_kernel(const float* __restrict__ x,
                                                   const float* __restrict__ w_is,
                                                   __half* __restrict__ zph) {
  const int b = blockIdx.x >> 6;
  const int r = blockIdx.x & 63;
  const int tid = threadIdx.x;
  __shared__ __align__(16) float xt[64][132];  // [w][c]
  __shared__ __align__(16) float wt[32][132];  // [o][c] per 32-O chunk

#pragma unroll
  for (int i = 0; i < 8; i++) {
    int idx = tid + i * 256;  // 0..2047
    int c = idx >> 4;
    int w4 = idx & 15;
    float4 v = *(const float4*)&x[(((size_t)b * 128 + c) * HH + r) * WW + 4 * w4];
    xt[4 * w4 + 0][c] = v.x;
    xt[4 * w4 + 1][c] = v.y;
    xt[4 * w4 + 2][c] = v.z;
    xt[4 * w4 + 3][c] = v.w;
  }

  const int op = tid & 15;
  const int wp = tid >> 4;
  const size_t obase = ((size_t)b * HH + r) * WW;

  for (int oc = 0; oc < 16; oc++) {
    __syncthreads();
#pragma unroll
    for (int i = 0; i < 4; i++) {
      int idx = tid + i * 256;  // 0..1023
      int o = idx >> 5;
      int k4 = idx & 31;
      *(float4*)&wt[o][4 * k4] =
          *(const float4*)&w_is[((size_t)(oc * 32 + o)) * 128 + 4 * k4];
    }
    __syncthreads();
    float acc[4][2];
#pragma unroll
    for (int wi = 0; wi < 4; wi++)
#pragma unroll
      for (int oi = 0; oi < 2; oi++) acc[wi][oi] = 0.f;
#pragma unroll
    for (int kg = 0; kg < 32; kg++) {
      float4 xv[4], wv[2];
#pragma unroll
      for (int wi = 0; wi < 4; wi++) xv[wi] = *(float4*)&xt[wp + 16 * wi][4 * kg];
#pragma unroll
      for (int oi = 0; oi < 2; oi++) wv[oi] = *(float4*)&wt[op + 16 * oi][4 * kg];
#pragma unroll
      for (int wi = 0; wi < 4; wi++)
#pragma unroll
        for (int oi = 0; oi < 2; oi++) {
          acc[wi][oi] += xv[wi].x * wv[oi].x + xv[wi].y * wv[oi].y +
                         xv[wi].z * wv[oi].z + xv[wi].w * wv[oi].w;
        }
    }
#pragma unroll
    for (int wi = 0; wi < 4; wi++)
#pragma unroll
      for (int oi = 0; oi < 2; oi++) {
        int O = oc * 32 + op + 16 * oi;
        int u = O & 127;
        int g = O >> 7;
        zph[(obase + wp + 16 * wi) * 512 + u * 4 + g] = __float2half(acc[wi][oi]);
      }
  }
}

// ---------------- weight prep: Wcat(512x256) fp32 -> f16 A-fragments --------
__global__ __launch_bounds__(256) void prep_w(const float* __restrict__ w_ss,
                                              _Float16* __restrict__ wp) {
  int i = blockIdx.x * 256 + threadIdx.x;  // 0..131071
  int j = i & 7;
  int L = (i >> 3) & 63;
  int kt = (i >> 9) & 7;
  int mt = i >> 12;  // 0..31
  int O = mt * 16 + (L & 15);
  int k = kt * 32 + ((L >> 4) & 3) * 8 + j;
  float v = (k < 128) ? w_ss[(size_t)O * 256 + k * 2]
                      : w_ss[(size_t)O * 256 + (k - 128) * 2 + 1];
  wp[i] = (_Float16)v;
}

// ---------------- persistent MFMA recurrent kernel ----------------
#define HROW 136  // padded row stride in halfs

__global__ __launch_bounds__(512, 1) void lstm_mfma(
    const __half* __restrict__ zph, const _Float16* __restrict__ wp,
    const float* __restrict__ b_is, const float* __restrict__ b_ss,
    unsigned long long* __restrict__ hx,  // [TT][8][4][64] boundary rows
    unsigned* __restrict__ flags8,        // [TT][8][4][8] per-wave, init 0
    float* __restrict__ out) {
  const int blk = blockIdx.x;  // 0..31
  const int rgr = blk >> 2;    // row group 0..7 (rows 8*rgr .. +7)
  const int bg = blk & 3;      // batch group 0..3 (b = 2*bg, 2*bg+1)
  const int R0 = rgr * 8;
  const int tid = threadIdx.x;
  const int wv = tid >> 6;  // wave 0..7
  const int L = tid & 63;
  const int quad = L >> 4;
  const int l15 = L & 15;
  const int rl = l15 >> 1;  // cell row-local 0..7
  const int bl = l15 & 1;   // cell batch-local 0..1
  const int b = bg * 2 + bl;
  const int r = R0 + rl;
  const int uq0 = 16 * wv + quad * 4;  // D-side unit base (+reg)

  // double-buffered: slot s holds row R0-1+s (s=0..8), per b-local
  __shared__ _Float16 h_lds[2][9 * 2 * HROW];
  for (int i = tid; i < (2 * 9 * 2 * HROW) / 2; i += 512)
    ((unsigned*)h_lds)[i] = 0u;

  // ---- weights into regs as A-fragments, once (128 VGPR/lane) ----
  v8h wfrag[4][8];
  {
    const v8h* wp8 = (const v8h*)wp;
#pragma unroll
    for (int g = 0; g < 4; g++)
#pragma unroll
      for (int kt = 0; kt < 8; kt++)
        wfrag[g][kt] = wp8[((size_t)((8 * g + wv) * 8 + kt)) * 64 + L];
  }

  float bsum[4][4];
#pragma unroll
  for (int g = 0; g < 4; g++)
#pragma unroll
    for (int rg2 = 0; rg2 < 4; rg2++) {
      int O = g * 128 + uq0 + rg2;
      bsum[g][rg2] = b_is[O] + b_ss[O];
    }

  float c[4] = {0.f, 0.f, 0.f, 0.f};
  float4 outb[4];  // shift-window out buffer (w-3..w per cell)
#pragma unroll
  for (int i = 0; i < 4; i++) outb[i] = make_float4(0.f, 0.f, 0.f, 0.f);

  const int ebl = L >> 5;       // boundary-exchange consumer: b-local
  const int eu = (L & 31) * 4;  // boundary-exchange consumer: unit base
  const int exp_idx = bl * 32 + 4 * wv + quad;  // producer slot (l15>=14)

  // ---- zp for t=0 ----
  union ZU {
    uint4 q[2];
    __half h[16];
  } zu;
  zu.q[0] = (uint4){0u, 0u, 0u, 0u};
  zu.q[1] = (uint4){0u, 0u, 0u, 0u};
  if (r == 0) {  // w = 0 - r in band only for r==0
    const uint4* p = (const uint4*)(zph + ((size_t)b * HH * WW) * 512 + uq0 * 4);
    zu.q[0] = p[0];
    zu.q[1] = p[1];
  }

  __syncthreads();

  for (int t = 0; t < TT; t++) {
    const int rb = t & 1;
    const int wb = rb ^ 1;

    // ---- wave0: prefetch boundary h(t)[R0-1] for step t+1 (poll at top,
    //      load overlapped with own MFMA) ----
    unsigned long long hxv = 0ull;
    const bool fetchb = (wv == 0) && (rgr > 0) && (t + 1 < TT);
    if (fetchb) {
      const unsigned* fb = flags8 + (((size_t)t * 8 + (rgr - 1)) * 4 + bg) * 8;
      for (;;) {
        unsigned v = (L < 8) ? __hip_atomic_load(&fb[L], __ATOMIC_RELAXED,
                                                 __HIP_MEMORY_SCOPE_AGENT)
                             : 1u;
        if (__ballot(v == 0u) == 0ull) break;
        __builtin_amdgcn_s_sleep(1);
      }
      hxv = __hip_atomic_load(
          &hx[(((size_t)t * 8 + (rgr - 1)) * 4 + bg) * 64 + L],
          __ATOMIC_RELAXED, __HIP_MEMORY_SCOPE_AGENT);
    }

    // ---- MFMA: kt 0..3 -> rows r-1 (slot rl); kt 4..7 -> rows r (slot rl+1)
    v4f acc[4];
#pragma unroll
    for (int g = 0; g < 4; g++) acc[g] = (v4f){0.f, 0.f, 0.f, 0.f};
#pragma unroll
    for (int kt = 0; kt < 8; kt++) {
      const int slot = (kt < 4) ? rl : (rl + 1);
      v8h bf = *(const v8h*)&h_lds[rb][(slot * 2 + bl) * HROW +
                                       (kt & 3) * 32 + quad * 8];
#pragma unroll
      for (int g = 0; g < 4; g++)
        acc[g] = __builtin_amdgcn_mfma_f32_16x16x32_f16(wfrag[g][kt], bf,
                                                        acc[g], 0, 0, 0);
    }

    // ---- gates (in-register; lane owns cell (r,b), units uq0..uq0+3) ----
    const int w = t - r;
    const bool inband = (w >= 0) && (w < WW);
    float hv[4];
#pragma unroll
    for (int rg2 = 0; rg2 < 4; rg2++) {
      float z0 = acc[0][rg2] + bsum[0][rg2] + __half2float(zu.h[rg2 * 4 + 0]);
      float z1 = acc[1][rg2] + bsum[1][rg2] + __half2float(zu.h[rg2 * 4 + 1]);
      float z2 = acc[2][rg2] + bsum[2][rg2] + __half2float(zu.h[rg2 * 4 + 2]);
      float z3 = acc[3][rg2] + bsum[3][rg2] + __half2float(zu.h[rg2 * 4 + 3]);
      float iv = fsig(z0);
      float fv = fsig(z1);
      float ov = fsig(z2);
      float gv = ftanh_(z3);
      c[rg2] = fv * c[rg2] + iv * gv;
      hv[rg2] = ov * ftanh_(c[rg2]);
    }

    // ---- h(t) -> wb slots 1..8 (LDS, 8B per lane) ----
    {
      __half2 lo = __floats2half2_rn(hv[0], hv[1]);
      __half2 hi = __floats2half2_rn(hv[2], hv[3]);
      uint2 pk;
      pk.x = *(unsigned*)&lo;
      pk.y = *(unsigned*)&hi;
      *(uint2*)&h_lds[wb][((rl + 1) * 2 + bl) * HROW + uq0] = pk;
    }

    // ---- wave0: boundary -> wb slot 0 (compiler waits the hx load) ----
    if (fetchb) {
      *(unsigned long long*)&h_lds[wb][(0 * 2 + ebl) * HROW + eu] = hxv;
    }

    // ---- lazy flag for export t-1, then export h(t)[R0+7] ----
    if (rgr < 7) {
      if (t > 0) {
        __builtin_amdgcn_s_waitcnt(0x0f70);  // vmcnt(0): 1-step-old ops, ~free
        if (L == 14) {
          __hip_atomic_store(
              &flags8[(((size_t)(t - 1) * 8 + rgr) * 4 + bg) * 8 + wv], 1u,
              __ATOMIC_RELAXED, __HIP_MEMORY_SCOPE_AGENT);
        }
      }
      if (l15 >= 14) {  // lanes owning row R0+7 (rl==7), both b
        __half2 lo = __floats2half2_rn(hv[0], hv[1]);
        __half2 hi = __floats2half2_rn(hv[2], hv[3]);
        unsigned long long pk =
            ((unsigned long long)*(unsigned*)&hi << 32) | *(unsigned*)&lo;
        __hip_atomic_store(&hx[(((size_t)t * 8 + rgr) * 4 + bg) * 64 + exp_idx],
                           pk, __ATOMIC_RELAXED, __HIP_MEMORY_SCOPE_AGENT);
      }
    }

    // ---- out shift-window; coalesced 16B flush every 4 steps per cell ----
#pragma unroll
    for (int rg2 = 0; rg2 < 4; rg2++) {
      outb[rg2].x = outb[rg2].y;
      outb[rg2].y = outb[rg2].z;
      outb[rg2].z = outb[rg2].w;
      outb[rg2].w = hv[rg2];
    }
    if (inband && (w & 3) == 3) {
      float* op_ = out + (((size_t)b * HID + uq0) * HH + r) * WW + (w - 3);
#pragma unroll
      for (int rg2 = 0; rg2 < 4; rg2++) {
        *(float4*)(op_ + (size_t)rg2 * (HH * WW)) = outb[rg2];
      }
    }

    // ---- zp prefetch for t+1 (after flag/export: not in drain set) ----
    {
      const int wn = t + 1 - r;
      if (wn >= 0 && wn < WW) {
        const uint4* p =
            (const uint4*)(zph + (((size_t)b * HH + r) * WW + wn) * 512 + uq0 * 4);
        zu.q[0] = p[0];
        zu.q[1] = p[1];
      } else {
        zu.q[0] = (uint4){0u, 0u, 0u, 0u};
        zu.q[1] = (uint4){0u, 0u, 0u, 0u};
      }
    }

    __syncthreads();  // wb complete; rb free for rewrite next step
  }
}

// ================= round-1 fallback path (proven correct) =================
__global__ __launch_bounds__(256) void transpose_x(const float* __restrict__ x,
                                                   float* __restrict__ xT) {
  int b = blockIdx.x >> 6;
  int r = blockIdx.x & 63;
  __shared__ float tile[32][65];
  for (int cc = 0; cc < 4; cc++) {
    int cl = threadIdx.x >> 6;
    int w = threadIdx.x & 63;
#pragma unroll
    for (int k = 0; k < 8; k++) {
      int c_loc = k * 4 + cl;
      int c = cc * 32 + c_loc;
      tile[c_loc][w] = x[(((size_t)b * 128 + c) * HH + r) * WW + w];
    }
    __syncthreads();
    int cs = threadIdx.x & 31;
    int wp = threadIdx.x >> 5;
#pragma unroll
    for (int k = 0; k < 8; k++) {
      int w2 = wp * 8 + k;
      xT[(((size_t)b * HH + r) * WW + w2) * 128 + cc * 32 + cs] = tile[cs][w2];
    }
    __syncthreads();
  }
}

__global__ __launch_bounds__(256) void step_kernel(
    const float* __restrict__ x, const float* __restrict__ xT, int use_xT,
    const float* __restrict__ w_is, const float* __restrict__ b_is,
    const float* __restrict__ w_ss, const float* __restrict__ b_ss,
    const float* __restrict__ h_prev, float* __restrict__ h_next,
    float* __restrict__ c_state, float* __restrict__ out, int t) {
  const int rg = blockIdx.x;
  const int q = blockIdx.y;
  const int r0 = rg * 2;
  const int tid = threadIdx.x;
  const int o_loc = tid & 63;
  const int k4 = tid >> 6;
  const int g_ = o_loc >> 4;
  const int u_ = o_loc & 15;
  const int O = g_ * 128 + q * 16 + u_;
  const int i0 = k4 * 32;

  __shared__ __align__(16) float h_in[3][BB][HID];
  __shared__ float zred[16][4][65];

  for (int idx = tid; idx < 3 * BB * HID; idx += 256) {
    int row_sel = idx >> 10;
    int rem = idx & 1023;
    int b = rem >> 7;
    int u = rem & 127;
    int rr = r0 - 1 + row_sel;
    h_in[row_sel][b][u] = (rr >= 0) ? h_prev[((size_t)b * HH + rr) * HID + u] : 0.0f;
  }

  float wr0[32], wr1[32], wz[32];
  {
    const float4* wss4 = (const float4*)(w_ss + ((size_t)O * 128 + i0) * 2);
#pragma unroll
    for (int j = 0; j < 16; j++) {
      float4 v = wss4[j];
      wr0[2 * j] = v.x;
      wr1[2 * j] = v.y;
      wr0[2 * j + 1] = v.z;
      wr1[2 * j + 1] = v.w;
    }
    const float4* wis4 = (const float4*)(w_is + (size_t)O * 128 + i0);
#pragma unroll
    for (int j = 0; j < 8; j++) {
      float4 v = wis4[j];
      wz[4 * j] = v.x;
      wz[4 * j + 1] = v.y;
      wz[4 * j + 2] = v.z;
      wz[4 * j + 3] = v.w;
    }
  }

  __syncthreads();

  float acc[2][BB];
#pragma unroll
  for (int rl = 0; rl < 2; rl++)
#pragma unroll
    for (int b = 0; b < BB; b++) acc[rl][b] = 0.0f;

#pragma unroll
  for (int jb = 0; jb < 8; jb++) {
    int ib = i0 + jb * 4;
#pragma unroll
    for (int b = 0; b < BB; b++) {
      const float4 hm4 = *(const float4*)&h_in[0][b][ib];
      const float4 hc4 = *(const float4*)&h_in[1][b][ib];
      const float4 hp4 = *(const float4*)&h_in[2][b][ib];
      const float* hm = (const float*)&hm4;
      const float* hc = (const float*)&hc4;
      const float* hq = (const float*)&hp4;
#pragma unroll
      for (int jj = 0; jj < 4; jj++) {
        float w0v = wr0[jb * 4 + jj];
        float w1v = wr1[jb * 4 + jj];
        acc[0][b] += w0v * hm[jj] + w1v * hc[jj];
        acc[1][b] += w0v * hc[jj] + w1v * hq[jj];
      }
    }
  }

#pragma unroll
  for (int rl = 0; rl < 2; rl++) {
    int rr = r0 + rl;
    int wcol = t - rr;
    if (wcol >= 0 && wcol < WW) {
      if (use_xT) {
        for (int b = 0; b < BB; b++) {
          const float4* xp =
              (const float4*)(xT + (((size_t)b * HH + rr) * WW + wcol) * 128 + i0);
#pragma unroll
          for (int j = 0; j < 8; j++) {
            float4 v = xp[j];
            acc[rl][b] += wz[4 * j] * v.x + wz[4 * j + 1] * v.y +
                          wz[4 * j + 2] * v.z + wz[4 * j + 3] * v.w;
          }
        }
      } else {
        for (int b = 0; b < BB; b++) {
          const float* xb = x + (((size_t)b * 128 + i0) * HH + rr) * WW + wcol;
#pragma unroll
          for (int j = 0; j < 32; j++) {
            acc[rl][b] += wz[j] * xb[(size_t)j * HH * WW];
          }
        }
      }
    }
  }

#pragma unroll
  for (int rl = 0; rl < 2; rl++)
#pragma unroll
    for (int b = 0; b < BB; b++) zred[rl * 8 + b][k4][o_loc] = acc[rl][b];
  __syncthreads();

  {
    int u = tid >> 4;
    int cell = tid & 15;
    int rl = cell >> 3;
    int b = cell & 7;
    int rr = r0 + rl;
    float z[4];
#pragma unroll
    for (int gg = 0; gg < 4; gg++) {
      int ol = gg * 16 + u;
      float s = zred[cell][0][ol] + zred[cell][1][ol] + zred[cell][2][ol] +
                zred[cell][3][ol];
      int Og = gg * 128 + q * 16 + u;
      z[gg] = s + b_is[Og] + b_ss[Og];
    }
    float iv = 1.0f / (1.0f + expf(-z[0]));
    float fv = 1.0f / (1.0f + expf(-z[1]));
    float ov = 1.0f / (1.0f + expf(-z[2]));
    float gv = tanhf(z[3]);
    int U = q * 16 + u;
    size_t sidx = ((size_t)b * HH + rr) * HID + U;
    float cv = c_state[sidx];
    float cn = fv * cv + iv * gv;
    c_state[sidx] = cn;
    float hn = ov * tanhf(cn);
    h_next[sidx] = hn;
    int wcol = t - rr;
    if (wcol >= 0 && wcol < WW) {
      out[(((size_t)b * HID + U) * HH + rr) * WW + wcol] = hn;
    }
  }
}

extern "C" void kernel_launch(void* const* d_in, const int* in_sizes, int n_in,
                              void* d_out, int out_size, void* d_ws,
                              size_t ws_size, hipStream_t stream) {
  const float* x = (const float*)d_in[0];
  const float* w_is = (const float*)d_in[1];
  const float* b_is = (const float*)d_in[2];
  const float* w_ss = (const float*)d_in[3];
  const float* b_ss = (const float*)d_in[4];
  float* outp = (float*)d_out;

  const size_t zph_bytes = (size_t)BB * HH * WW * 512 * 2;  // 32 MiB
  const size_t wp_bytes = (size_t)512 * 256 * 2;            // 256 KiB
  const size_t hx_bytes = (size_t)TT * 8 * 4 * 64 * 8;      // ~2.03 MiB
  const size_t fl_bytes = (size_t)TT * 8 * 4 * 8 * 4;       // ~127 KiB
  const size_t need = zph_bytes + wp_bytes + hx_bytes + fl_bytes;

  char* ws = (char*)d_ws;
  if (ws_size >= need) {
    __half* zph = (__half*)ws;
    _Float16* wpp = (_Float16*)(ws + zph_bytes);
    unsigned long long* hx = (unsigned long long*)(ws + zph_bytes + wp_bytes);
    unsigned* flags8 = (unsigned*)(ws + zph_bytes + wp_bytes + hx_bytes);

    hipMemsetAsync(flags8, 0, fl_bytes, stream);
    zpre_kernel<<<dim3(BB * HH), 256, 0, stream>>>(x, w_is, zph);
    prep_w<<<dim3(512), 256, 0, stream>>>(w_ss, wpp);
    lstm_mfma<<<dim3(32), 512, 0, stream>>>(zph, wpp, b_is, b_ss, hx, flags8,
                                            outp);
  } else {
    // -------- round-1 fallback --------
    const size_t xT_elems = (size_t)BB * HH * WW * 128;
    const size_t st_elems = (size_t)BB * HH * HID;
    const size_t need_xT = (xT_elems + 3 * st_elems) * sizeof(float);
    float* wsf = (float*)d_ws;
    float* xT = nullptr;
    float* st;
    int use_xT = 0;
    if (ws_size >= need_xT) {
      use_xT = 1;
      xT = wsf;
      st = wsf + xT_elems;
    } else {
      st = wsf;
    }
    float* h0 = st;
    float* h1 = st + st_elems;
    float* cb = st + 2 * st_elems;
    hipMemsetAsync(st, 0, 3 * st_elems * sizeof(float), stream);
    if (use_xT) transpose_x<<<dim3(BB * HH), 256, 0, stream>>>(x, xT);
    for (int t = 0; t < TT; t++) {
      float* hp = (t & 1) ? h1 : h0;
      float* hn = (t & 1) ? h0 : h1;
      step_kernel<<<dim3(32, 8), 256, 0, stream>>>(x, xT, use_xT, w_is, b_is,
                                                   w_ss, b_ss, hp, hn, cb, outp,
                                                   t);
    }
  }
}

// Round 8
// 392.984 us; speedup vs baseline: 11.9165x; 1.0905x over previous
//
#include <hip/hip_runtime.h>
#include <hip/hip_fp16.h>
#include <math.h>

// DiagonalLSTM: B=8, Cin=HID=128, H=64, W=64, K=2, T = 2W-1 = 127 steps.
//
// Round 8 design (round 7 + MFMA prologue):
//   - zpre_mfma: z_is via mfma_f32_16x16x32_f16 per (b,r): M=512,N=64,K=128.
//     x-tile staged to LDS f16 transposed [w][c]; B-frags cached in regs
//     across the M loop; A-frags (w_is) pre-laid-out by prep_all -> one
//     coalesced 16B load per (mt,kt). zph layout now plain O-major.
//   - prep_all: w_ss A-frags + w_is A-frags + flags zeroing in one dispatch.
//   - lstm_mfma: round-7 structure (single barrier/step, boundary prefetch
//     1 step ahead, lazy flags, reg-buffered out stores); zp prefetch now
//     4x8B loads (O-major layout), still 1 step ahead.

#define HID 128
#define BB 8
#define HH 64
#define WW 64
#define TT 127

typedef _Float16 v8h __attribute__((ext_vector_type(8)));
typedef float v4f __attribute__((ext_vector_type(4)));

__device__ __forceinline__ float fsig(float x) {
  x = __builtin_fmaxf(__builtin_fminf(x, 30.f), -30.f);
  float e = __builtin_amdgcn_exp2f(x * -1.44269504f);
  return __builtin_amdgcn_rcpf(1.f + e);
}
__device__ __forceinline__ float ftanh_(float x) {
  x = __builtin_fmaxf(__builtin_fminf(x, 15.f), -15.f);
  float e = __builtin_amdgcn_exp2f(x * 2.88539009f);
  return (e - 1.f) * __builtin_amdgcn_rcpf(e + 1.f);
}

// ---- prep_all: w_ss frags (131072) + w_is frags (65536) + flags zero ----
__global__ __launch_bounds__(256) void prep_all(const float* __restrict__ w_ss,
                                                const float* __restrict__ w_is,
                                                _Float16* __restrict__ wp,
                                                _Float16* __restrict__ wisa,
                                                unsigned* __restrict__ flags8) {
  int idx = blockIdx.x * 256 + threadIdx.x;
  if (idx < 131072) {
    // w_ss -> Wcat(512x256) A-frags: wp[(((mt*8+kt)*64+L)*8+j)]
    int j = idx & 7;
    int L = (idx >> 3) & 63;
    int kt = (idx >> 9) & 7;
    int mt = idx >> 12;  // 0..31
    int O = mt * 16 + (L & 15);
    int k = kt * 32 + ((L >> 4) & 3) * 8 + j;
    float v = (k < 128) ? w_ss[(size_t)O * 256 + k * 2]
                        : w_ss[(size_t)O * 256 + (k - 128) * 2 + 1];
    wp[idx] = (_Float16)v;
  } else if (idx < 196608) {
    // w_is (512x128) A-frags: wisa[(((mt*4+kt)*64+L)*8+j)]
    int i2 = idx - 131072;
    int j = i2 & 7;
    int L = (i2 >> 3) & 63;
    int kt = (i2 >> 9) & 3;
    int mt = i2 >> 11;  // 0..31
    int O = mt * 16 + (L & 15);
    int k = kt * 32 + ((L >> 4) & 3) * 8 + j;
    wisa[i2] = (_Float16)w_is[(size_t)O * 128 + k];
  } else if (idx < 196608 + TT * 8 * 4 * 8) {
    flags8[idx - 196608] = 0u;
  }
}

// ---- zpre_mfma: zph[(b,r,w)*512 + O] = sum_c w_is[O][c] x[b,c,r,w] ----
__global__ __launch_bounds__(256) void zpre_mfma(const float* __restrict__ x,
                                                 const _Float16* __restrict__ wisa,
                                                 __half* __restrict__ zph) {
  const int b = blockIdx.x >> 6;
  const int r = blockIdx.x & 63;
  const int tid = threadIdx.x;
  const int wv = tid >> 6;  // 0..3 -> ntile
  const int L = tid & 63;
  const int quad = L >> 4;
  const int l15 = L & 15;

  __shared__ _Float16 xt[64][136];  // [w][c] f16, padded

  // stage x(b,:,r,:) -> xt transposed (f32 -> f16)
  {
    int c = tid >> 1;
    int wh = (tid & 1) * 32;
    const float4* xs =
        (const float4*)&x[(((size_t)b * 128 + c) * HH + r) * WW + wh];
#pragma unroll
    for (int i = 0; i < 8; i++) {
      float4 v = xs[i];
      xt[wh + 4 * i + 0][c] = (_Float16)v.x;
      xt[wh + 4 * i + 1][c] = (_Float16)v.y;
      xt[wh + 4 * i + 2][c] = (_Float16)v.z;
      xt[wh + 4 * i + 3][c] = (_Float16)v.w;
    }
  }
  __syncthreads();

  const int wcol = wv * 16 + l15;  // B-side n
  v8h bf[4];
#pragma unroll
  for (int kt = 0; kt < 4; kt++)
    bf[kt] = *(const v8h*)&xt[wcol][kt * 32 + quad * 8];

  const size_t pos = ((size_t)b * HH + r) * WW + wcol;
  const v8h* wa8 = (const v8h*)wisa;

#pragma unroll 4
  for (int mt = 0; mt < 32; mt++) {
    v4f acc = (v4f){0.f, 0.f, 0.f, 0.f};
#pragma unroll
    for (int kt = 0; kt < 4; kt++) {
      v8h af = wa8[((size_t)mt * 4 + kt) * 64 + L];
      acc = __builtin_amdgcn_mfma_f32_16x16x32_f16(af, bf[kt], acc, 0, 0, 0);
    }
    // D: m = quad*4+reg (O local), n = l15 -> 4 consecutive O = 8B store
    __half2 lo = __floats2half2_rn(acc[0], acc[1]);
    __half2 hi = __floats2half2_rn(acc[2], acc[3]);
    uint2 pk;
    pk.x = *(unsigned*)&lo;
    pk.y = *(unsigned*)&hi;
    *(uint2*)&zph[pos * 512 + mt * 16 + quad * 4] = pk;
  }
}

// ---------------- persistent MFMA recurrent kernel ----------------
#define HROW 136  // padded row stride in halfs

__global__ __launch_bounds__(512, 1) void lstm_mfma(
    const __half* __restrict__ zph, const _Float16* __restrict__ wp,
    const float* __restrict__ b_is, const float* __restrict__ b_ss,
    unsigned long long* __restrict__ hx,  // [TT][8][4][64] boundary rows
    unsigned* __restrict__ flags8,        // [TT][8][4][8] per-wave, init 0
    float* __restrict__ out) {
  const int blk = blockIdx.x;  // 0..31
  const int rgr = blk >> 2;    // row group 0..7 (rows 8*rgr .. +7)
  const int bg = blk & 3;      // batch group 0..3 (b = 2*bg, 2*bg+1)
  const int R0 = rgr * 8;
  const int tid = threadIdx.x;
  const int wv = tid >> 6;  // wave 0..7
  const int L = tid & 63;
  const int quad = L >> 4;
  const int l15 = L & 15;
  const int rl = l15 >> 1;  // cell row-local 0..7
  const int bl = l15 & 1;   // cell batch-local 0..1
  const int b = bg * 2 + bl;
  const int r = R0 + rl;
  const int uq0 = 16 * wv + quad * 4;  // D-side unit base (+reg)

  // double-buffered: slot s holds row R0-1+s (s=0..8), per b-local
  __shared__ _Float16 h_lds[2][9 * 2 * HROW];
  for (int i = tid; i < (2 * 9 * 2 * HROW) / 2; i += 512)
    ((unsigned*)h_lds)[i] = 0u;

  // ---- weights into regs as A-fragments, once (128 VGPR/lane) ----
  v8h wfrag[4][8];
  {
    const v8h* wp8 = (const v8h*)wp;
#pragma unroll
    for (int g = 0; g < 4; g++)
#pragma unroll
      for (int kt = 0; kt < 8; kt++)
        wfrag[g][kt] = wp8[((size_t)((8 * g + wv) * 8 + kt)) * 64 + L];
  }

  float bsum[4][4];
#pragma unroll
  for (int g = 0; g < 4; g++)
#pragma unroll
    for (int rg2 = 0; rg2 < 4; rg2++) {
      int O = g * 128 + uq0 + rg2;
      bsum[g][rg2] = b_is[O] + b_ss[O];
    }

  float c[4] = {0.f, 0.f, 0.f, 0.f};
  float4 outb[4];  // shift-window out buffer (w-3..w per cell)
#pragma unroll
  for (int i = 0; i < 4; i++) outb[i] = make_float4(0.f, 0.f, 0.f, 0.f);

  const int ebl = L >> 5;       // boundary-exchange consumer: b-local
  const int eu = (L & 31) * 4;  // boundary-exchange consumer: unit base
  const int exp_idx = bl * 32 + 4 * wv + quad;  // producer slot (l15>=14)

  // ---- zp for t=0 (O-major layout: 4 x 8B, gate stride 128 halfs) ----
  union ZU {
    uint2 q[4];
    __half h[16];  // h[g*4 + rg2]
  } zu;
#pragma unroll
  for (int g = 0; g < 4; g++) zu.q[g] = (uint2){0u, 0u};
  if (r == 0) {
    const uint2* p2 = (const uint2*)(zph + ((size_t)b * HH * WW) * 512 + uq0);
#pragma unroll
    for (int g = 0; g < 4; g++) zu.q[g] = p2[g * 32];
  }

  __syncthreads();

  for (int t = 0; t < TT; t++) {
    const int rb = t & 1;
    const int wb = rb ^ 1;

    // ---- wave0: prefetch boundary h(t)[R0-1] for step t+1 (poll at top,
    //      load overlapped with own MFMA) ----
    unsigned long long hxv = 0ull;
    const bool fetchb = (wv == 0) && (rgr > 0) && (t + 1 < TT);
    if (fetchb) {
      const unsigned* fb = flags8 + (((size_t)t * 8 + (rgr - 1)) * 4 + bg) * 8;
      for (;;) {
        unsigned v = (L < 8) ? __hip_atomic_load(&fb[L], __ATOMIC_RELAXED,
                                                 __HIP_MEMORY_SCOPE_AGENT)
                             : 1u;
        if (__ballot(v == 0u) == 0ull) break;
        __builtin_amdgcn_s_sleep(1);
      }
      hxv = __hip_atomic_load(
          &hx[(((size_t)t * 8 + (rgr - 1)) * 4 + bg) * 64 + L],
          __ATOMIC_RELAXED, __HIP_MEMORY_SCOPE_AGENT);
    }

    // ---- MFMA: kt 0..3 -> rows r-1 (slot rl); kt 4..7 -> rows r (slot rl+1)
    v4f acc[4];
#pragma unroll
    for (int g = 0; g < 4; g++) acc[g] = (v4f){0.f, 0.f, 0.f, 0.f};
#pragma unroll
    for (int kt = 0; kt < 8; kt++) {
      const int slot = (kt < 4) ? rl : (rl + 1);
      v8h bf = *(const v8h*)&h_lds[rb][(slot * 2 + bl) * HROW +
                                       (kt & 3) * 32 + quad * 8];
#pragma unroll
      for (int g = 0; g < 4; g++)
        acc[g] = __builtin_amdgcn_mfma_f32_16x16x32_f16(wfrag[g][kt], bf,
                                                        acc[g], 0, 0, 0);
    }

    // ---- gates (in-register; lane owns cell (r,b), units uq0..uq0+3) ----
    const int w = t - r;
    const bool inband = (w >= 0) && (w < WW);
    float hv[4];
#pragma unroll
    for (int rg2 = 0; rg2 < 4; rg2++) {
      float z0 = acc[0][rg2] + bsum[0][rg2] + __half2float(zu.h[0 * 4 + rg2]);
      float z1 = acc[1][rg2] + bsum[1][rg2] + __half2float(zu.h[1 * 4 + rg2]);
      float z2 = acc[2][rg2] + bsum[2][rg2] + __half2float(zu.h[2 * 4 + rg2]);
      float z3 = acc[3][rg2] + bsum[3][rg2] + __half2float(zu.h[3 * 4 + rg2]);
      float iv = fsig(z0);
      float fv = fsig(z1);
      float ov = fsig(z2);
      float gv = ftanh_(z3);
      c[rg2] = fv * c[rg2] + iv * gv;
      hv[rg2] = ov * ftanh_(c[rg2]);
    }

    // ---- h(t) -> wb slots 1..8 (LDS, 8B per lane) ----
    {
      __half2 lo = __floats2half2_rn(hv[0], hv[1]);
      __half2 hi = __floats2half2_rn(hv[2], hv[3]);
      uint2 pk;
      pk.x = *(unsigned*)&lo;
      pk.y = *(unsigned*)&hi;
      *(uint2*)&h_lds[wb][((rl + 1) * 2 + bl) * HROW + uq0] = pk;
    }

    // ---- wave0: boundary -> wb slot 0 (compiler waits the hx load) ----
    if (fetchb) {
      *(unsigned long long*)&h_lds[wb][(0 * 2 + ebl) * HROW + eu] = hxv;
    }

    // ---- lazy flag for export t-1, then export h(t)[R0+7] ----
    if (rgr < 7) {
      if (t > 0) {
        __builtin_amdgcn_s_waitcnt(0x0f70);  // vmcnt(0): 1-step-old ops, ~free
        if (L == 14) {
          __hip_atomic_store(
              &flags8[(((size_t)(t - 1) * 8 + rgr) * 4 + bg) * 8 + wv], 1u,
              __ATOMIC_RELAXED, __HIP_MEMORY_SCOPE_AGENT);
        }
      }
      if (l15 >= 14) {  // lanes owning row R0+7 (rl==7), both b
        __half2 lo = __floats2half2_rn(hv[0], hv[1]);
        __half2 hi = __floats2half2_rn(hv[2], hv[3]);
        unsigned long long pk =
            ((unsigned long long)*(unsigned*)&hi << 32) | *(unsigned*)&lo;
        __hip_atomic_store(&hx[(((size_t)t * 8 + rgr) * 4 + bg) * 64 + exp_idx],
                           pk, __ATOMIC_RELAXED, __HIP_MEMORY_SCOPE_AGENT);
      }
    }

    // ---- out shift-window; coalesced 16B flush every 4 steps per cell ----
#pragma unroll
    for (int rg2 = 0; rg2 < 4; rg2++) {
      outb[rg2].x = outb[rg2].y;
      outb[rg2].y = outb[rg2].z;
      outb[rg2].z = outb[rg2].w;
      outb[rg2].w = hv[rg2];
    }
    if (inband && (w & 3) == 3) {
      float* op_ = out + (((size_t)b * HID + uq0) * HH + r) * WW + (w - 3);
#pragma unroll
      for (int rg2 = 0; rg2 < 4; rg2++) {
        *(float4*)(op_ + (size_t)rg2 * (HH * WW)) = outb[rg2];
      }
    }

    // ---- zp prefetch for t+1 (after flag/export: not in drain set) ----
    {
      const int wn = t + 1 - r;
      if (wn >= 0 && wn < WW) {
        const uint2* p2 =
            (const uint2*)(zph + (((size_t)b * HH + r) * WW + wn) * 512 + uq0);
#pragma unroll
        for (int g = 0; g < 4; g++) zu.q[g] = p2[g * 32];
      } else {
#pragma unroll
        for (int g = 0; g < 4; g++) zu.q[g] = (uint2){0u, 0u};
      }
    }

    __syncthreads();  // wb complete; rb free for rewrite next step
  }
}

// ================= round-1 fallback path (proven correct) =================
__global__ __launch_bounds__(256) void transpose_x(const float* __restrict__ x,
                                                   float* __restrict__ xT) {
  int b = blockIdx.x >> 6;
  int r = blockIdx.x & 63;
  __shared__ float tile[32][65];
  for (int cc = 0; cc < 4; cc++) {
    int cl = threadIdx.x >> 6;
    int w = threadIdx.x & 63;
#pragma unroll
    for (int k = 0; k < 8; k++) {
      int c_loc = k * 4 + cl;
      int c = cc * 32 + c_loc;
      tile[c_loc][w] = x[(((size_t)b * 128 + c) * HH + r) * WW + w];
    }
    __syncthreads();
    int cs = threadIdx.x & 31;
    int wp = threadIdx.x >> 5;
#pragma unroll
    for (int k = 0; k < 8; k++) {
      int w2 = wp * 8 + k;
      xT[(((size_t)b * HH + r) * WW + w2) * 128 + cc * 32 + cs] = tile[cs][w2];
    }
    __syncthreads();
  }
}

__global__ __launch_bounds__(256) void step_kernel(
    const float* __restrict__ x, const float* __restrict__ xT, int use_xT,
    const float* __restrict__ w_is, const float* __restrict__ b_is,
    const float* __restrict__ w_ss, const float* __restrict__ b_ss,
    const float* __restrict__ h_prev, float* __restrict__ h_next,
    float* __restrict__ c_state, float* __restrict__ out, int t) {
  const int rg = blockIdx.x;
  const int q = blockIdx.y;
  const int r0 = rg * 2;
  const int tid = threadIdx.x;
  const int o_loc = tid & 63;
  const int k4 = tid >> 6;
  const int g_ = o_loc >> 4;
  const int u_ = o_loc & 15;
  const int O = g_ * 128 + q * 16 + u_;
  const int i0 = k4 * 32;

  __shared__ __align__(16) float h_in[3][BB][HID];
  __shared__ float zred[16][4][65];

  for (int idx = tid; idx < 3 * BB * HID; idx += 256) {
    int row_sel = idx >> 10;
    int rem = idx & 1023;
    int b = rem >> 7;
    int u = rem & 127;
    int rr = r0 - 1 + row_sel;
    h_in[row_sel][b][u] = (rr >= 0) ? h_prev[((size_t)b * HH + rr) * HID + u] : 0.0f;
  }

  float wr0[32], wr1[32], wz[32];
  {
    const float4* wss4 = (const float4*)(w_ss + ((size_t)O * 128 + i0) * 2);
#pragma unroll
    for (int j = 0; j < 16; j++) {
      float4 v = wss4[j];
      wr0[2 * j] = v.x;
      wr1[2 * j] = v.y;
      wr0[2 * j + 1] = v.z;
      wr1[2 * j + 1] = v.w;
    }
    const float4* wis4 = (const float4*)(w_is + (size_t)O * 128 + i0);
#pragma unroll
    for (int j = 0; j < 8; j++) {
      float4 v = wis4[j];
      wz[4 * j] = v.x;
      wz[4 * j + 1] = v.y;
      wz[4 * j + 2] = v.z;
      wz[4 * j + 3] = v.w;
    }
  }

  __syncthreads();

  float acc[2][BB];
#pragma unroll
  for (int rl = 0; rl < 2; rl++)
#pragma unroll
    for (int b = 0; b < BB; b++) acc[rl][b] = 0.0f;

#pragma unroll
  for (int jb = 0; jb < 8; jb++) {
    int ib = i0 + jb * 4;
#pragma unroll
    for (int b = 0; b < BB; b++) {
      const float4 hm4 = *(const float4*)&h_in[0][b][ib];
      const float4 hc4 = *(const float4*)&h_in[1][b][ib];
      const float4 hp4 = *(const float4*)&h_in[2][b][ib];
      const float* hm = (const float*)&hm4;
      const float* hc = (const float*)&hc4;
      const float* hq = (const float*)&hp4;
#pragma unroll
      for (int jj = 0; jj < 4; jj++) {
        float w0v = wr0[jb * 4 + jj];
        float w1v = wr1[jb * 4 + jj];
        acc[0][b] += w0v * hm[jj] + w1v * hc[jj];
        acc[1][b] += w0v * hc[jj] + w1v * hq[jj];
      }
    }
  }

#pragma unroll
  for (int rl = 0; rl < 2; rl++) {
    int rr = r0 + rl;
    int wcol = t - rr;
    if (wcol >= 0 && wcol < WW) {
      if (use_xT) {
        for (int b = 0; b < BB; b++) {
          const float4* xp =
              (const float4*)(xT + (((size_t)b * HH + rr) * WW + wcol) * 128 + i0);
#pragma unroll
          for (int j = 0; j < 8; j++) {
            float4 v = xp[j];
            acc[rl][b] += wz[4 * j] * v.x + wz[4 * j + 1] * v.y +
                          wz[4 * j + 2] * v.z + wz[4 * j + 3] * v.w;
          }
        }
      } else {
        for (int b = 0; b < BB; b++) {
          const float* xb = x + (((size_t)b * 128 + i0) * HH + rr) * WW + wcol;
#pragma unroll
          for (int j = 0; j < 32; j++) {
            acc[rl][b] += wz[j] * xb[(size_t)j * HH * WW];
          }
        }
      }
    }
  }

#pragma unroll
  for (int rl = 0; rl < 2; rl++)
#pragma unroll
    for (int b = 0; b < BB; b++) zred[rl * 8 + b][k4][o_loc] = acc[rl][b];
  __syncthreads();

  {
    int u = tid >> 4;
    int cell = tid & 15;
    int rl = cell >> 3;
    int b = cell & 7;
    int rr = r0 + rl;
    float z[4];
#pragma unroll
    for (int gg = 0; gg < 4; gg++) {
      int ol = gg * 16 + u;
      float s = zred[cell][0][ol] + zred[cell][1][ol] + zred[cell][2][ol] +
                zred[cell][3][ol];
      int Og = gg * 128 + q * 16 + u;
      z[gg] = s + b_is[Og] + b_ss[Og];
    }
    float iv = 1.0f / (1.0f + expf(-z[0]));
    float fv = 1.0f / (1.0f + expf(-z[1]));
    float ov = 1.0f / (1.0f + expf(-z[2]));
    float gv = tanhf(z[3]);
    int U = q * 16 + u;
    size_t sidx = ((size_t)b * HH + rr) * HID + U;
    float cv = c_state[sidx];
    float cn = fv * cv + iv * gv;
    c_state[sidx] = cn;
    float hn = ov * tanhf(cn);
    h_next[sidx] = hn;
    int wcol = t - rr;
    if (wcol >= 0 && wcol < WW) {
      out[(((size_t)b * HID + U) * HH + rr) * WW + wcol] = hn;
    }
  }
}

extern "C" void kernel_launch(void* const* d_in, const int* in_sizes, int n_in,
                              void* d_out, int out_size, void* d_ws,
                              size_t ws_size, hipStream_t stream) {
  const float* x = (const float*)d_in[0];
  const float* w_is = (const float*)d_in[1];
  const float* b_is = (const float*)d_in[2];
  const float* w_ss = (const float*)d_in[3];
  const float* b_ss = (const float*)d_in[4];
  float* outp = (float*)d_out;

  const size_t zph_bytes = (size_t)BB * HH * WW * 512 * 2;  // 32 MiB
  const size_t wp_bytes = (size_t)512 * 256 * 2;            // 256 KiB
  const size_t wisa_bytes = (size_t)512 * 128 * 2;          // 128 KiB
  const size_t hx_bytes = (size_t)TT * 8 * 4 * 64 * 8;      // ~2.03 MiB
  const size_t fl_bytes = (size_t)TT * 8 * 4 * 8 * 4;       // ~127 KiB
  const size_t need = zph_bytes + wp_bytes + wisa_bytes + hx_bytes + fl_bytes;

  char* ws = (char*)d_ws;
  if (ws_size >= need) {
    __half* zph = (__half*)ws;
    _Float16* wpp = (_Float16*)(ws + zph_bytes);
    _Float16* wisa = (_Float16*)(ws + zph_bytes + wp_bytes);
    unsigned long long* hx =
        (unsigned long long*)(ws + zph_bytes + wp_bytes + wisa_bytes);
    unsigned* flags8 =
        (unsigned*)(ws + zph_bytes + wp_bytes + wisa_bytes + hx_bytes);

    // prep_all covers 131072 + 65536 + 32512 = 229120 items -> 896 blocks
    prep_all<<<dim3(896), 256, 0, stream>>>(w_ss, w_is, wpp, wisa, flags8);
    zpre_mfma<<<dim3(BB * HH), 256, 0, stream>>>(x, wisa, zph);
    lstm_mfma<<<dim3(32), 512, 0, stream>>>(zph, wpp, b_is, b_ss, hx, flags8,
                                            outp);
  } else {
    // -------- round-1 fallback --------
    const size_t xT_elems = (size_t)BB * HH * WW * 128;
    const size_t st_elems = (size_t)BB * HH * HID;
    const size_t need_xT = (xT_elems + 3 * st_elems) * sizeof(float);
    float* wsf = (float*)d_ws;
    float* xT = nullptr;
    float* st;
    int use_xT = 0;
    if (ws_size >= need_xT) {
      use_xT = 1;
      xT = wsf;
      st = wsf + xT_elems;
    } else {
      st = wsf;
    }
    float* h0 = st;
    float* h1 = st + st_elems;
    float* cb = st + 2 * st_elems;
    hipMemsetAsync(st, 0, 3 * st_elems * sizeof(float), stream);
    if (use_xT) transpose_x<<<dim3(BB * HH), 256, 0, stream>>>(x, xT);
    for (int t = 0; t < TT; t++) {
      float* hp = (t & 1) ? h1 : h0;
      float* hn = (t & 1) ? h0 : h1;
      step_kernel<<<dim3(32, 8), 256, 0, stream>>>(x, xT, use_xT, w_is, b_is,
                                                   w_ss, b_ss, hp, hn, cb, outp,
                                                   t);
    }
  }
}

// Round 10
// 347.330 us; speedup vs baseline: 13.4828x; 1.1314x over previous
//
#include <hip/hip_runtime.h>
#include <hip/hip_fp16.h>
#include <math.h>

// DiagonalLSTM: B=8, Cin=HID=128, H=64, W=64, K=2, T = 2W-1 = 127 steps.
//
// Round 10 design (round 9 minus the inline-asm MFMA):
//   - MFMA via __builtin_amdgcn_mfma_f32_16x16x32_f16 (intrinsic -> compiler
//     inserts the MFMA->VALU hazard wait-states that the round-9 inline asm
//     bypassed, which corrupted results sporadically).
//   - KEPT from round 9: sentinel-fused boundary exchange (hx pre-filled with
//     f16-NaN; producer = ONE fire-and-forget relaxed 8B store, data == flag,
//     no waitcnt drain anywhere in the loop; consumer issues the load a full
//     step early and validates with a ballot-retry at step end) and the
//     lane-contiguous zph layout [pos][(u>>2)*16 + g*4 + (u&3)] (2x16B loads).
//   - Otherwise round-7/8 structure: 32 blocks (8 rgr x 4 bg) x 512 thr,
//     single barrier/step, reg-buffered out stores, MFMA prologue.

#define HID 128
#define BB 8
#define HH 64
#define WW 64
#define TT 127

typedef _Float16 v8h __attribute__((ext_vector_type(8)));
typedef float v4f __attribute__((ext_vector_type(4)));

#define SENT64 0x7E007E007E007E00ULL  // 4x f16 NaN: unreachable from packing

__device__ __forceinline__ float fsig(float x) {
  x = __builtin_fmaxf(__builtin_fminf(x, 30.f), -30.f);
  float e = __builtin_amdgcn_exp2f(x * -1.44269504f);
  return __builtin_amdgcn_rcpf(1.f + e);
}
__device__ __forceinline__ float ftanh_(float x) {
  x = __builtin_fmaxf(__builtin_fminf(x, 15.f), -15.f);
  float e = __builtin_amdgcn_exp2f(x * 2.88539009f);
  return (e - 1.f) * __builtin_amdgcn_rcpf(e + 1.f);
}

// ---- prep_all: w_ss frags + w_is frags + hx sentinel fill ----
__global__ __launch_bounds__(256) void prep_all(
    const float* __restrict__ w_ss, const float* __restrict__ w_is,
    _Float16* __restrict__ wp, _Float16* __restrict__ wisa,
    unsigned long long* __restrict__ hx) {
  int idx = blockIdx.x * 256 + threadIdx.x;
  if (idx < 131072) {
    // w_ss -> Wcat(512x256) A-frags: wp[(((mt*8+kt)*64+L)*8+j)]
    int j = idx & 7;
    int L = (idx >> 3) & 63;
    int kt = (idx >> 9) & 7;
    int mt = idx >> 12;  // 0..31
    int O = mt * 16 + (L & 15);
    int k = kt * 32 + ((L >> 4) & 3) * 8 + j;
    float v = (k < 128) ? w_ss[(size_t)O * 256 + k * 2]
                        : w_ss[(size_t)O * 256 + (k - 128) * 2 + 1];
    wp[idx] = (_Float16)v;
  } else if (idx < 196608) {
    // w_is (512x128) A-frags: wisa[(((mt*4+kt)*64+L)*8+j)]
    int i2 = idx - 131072;
    int j = i2 & 7;
    int L = (i2 >> 3) & 63;
    int kt = (i2 >> 9) & 3;
    int mt = i2 >> 11;  // 0..31
    int O = mt * 16 + (L & 15);
    int k = kt * 32 + ((L >> 4) & 3) * 8 + j;
    wisa[i2] = (_Float16)w_is[(size_t)O * 128 + k];
  } else if (idx < 196608 + TT * 8 * 4 * 64) {
    hx[idx - 196608] = SENT64;  // sentinel: "not yet produced"
  }
}

// ---- zpre_mfma: zph[pos*512 + (u>>2)*16 + g*4 + (u&3)] ----
__global__ __launch_bounds__(256) void zpre_mfma(const float* __restrict__ x,
                                                 const _Float16* __restrict__ wisa,
                                                 __half* __restrict__ zph) {
  const int b = blockIdx.x >> 6;
  const int r = blockIdx.x & 63;
  const int tid = threadIdx.x;
  const int wv = tid >> 6;  // 0..3 -> ntile
  const int L = tid & 63;
  const int quad = L >> 4;
  const int l15 = L & 15;

  __shared__ _Float16 xt[64][136];  // [w][c] f16, padded

  // stage x(b,:,r,:) -> xt transposed (f32 -> f16)
  {
    int c = tid >> 1;
    int wh = (tid & 1) * 32;
    const float4* xs =
        (const float4*)&x[(((size_t)b * 128 + c) * HH + r) * WW + wh];
#pragma unroll
    for (int i = 0; i < 8; i++) {
      float4 v = xs[i];
      xt[wh + 4 * i + 0][c] = (_Float16)v.x;
      xt[wh + 4 * i + 1][c] = (_Float16)v.y;
      xt[wh + 4 * i + 2][c] = (_Float16)v.z;
      xt[wh + 4 * i + 3][c] = (_Float16)v.w;
    }
  }
  __syncthreads();

  const int wcol = wv * 16 + l15;  // B-side n
  v8h bf[4];
#pragma unroll
  for (int kt = 0; kt < 4; kt++)
    bf[kt] = *(const v8h*)&xt[wcol][kt * 32 + quad * 8];

  const size_t pos = ((size_t)b * HH + r) * WW + wcol;
  const v8h* wa8 = (const v8h*)wisa;

#pragma unroll 4
  for (int mt = 0; mt < 32; mt++) {
    v4f acc = (v4f){0.f, 0.f, 0.f, 0.f};
#pragma unroll
    for (int kt = 0; kt < 4; kt++) {
      v8h af = wa8[((size_t)mt * 4 + kt) * 64 + L];
      acc = __builtin_amdgcn_mfma_f32_16x16x32_f16(af, bf[kt], acc, 0, 0, 0);
    }
    // m-local O = mt*16 + quad*4 + reg -> u = (mt&7)*16+quad*4+reg, g = mt>>3
    // store idx = ((u>>2)*16 + g*4 + (u&3)) = ((mt&7)*4+quad)*16 + g*4 + reg
    __half2 lo = __floats2half2_rn(acc[0], acc[1]);
    __half2 hi = __floats2half2_rn(acc[2], acc[3]);
    uint2 pk;
    pk.x = *(unsigned*)&lo;
    pk.y = *(unsigned*)&hi;
    *(uint2*)&zph[pos * 512 + ((mt & 7) * 4 + quad) * 16 + (mt >> 3) * 4] = pk;
  }
}

// ---------------- persistent MFMA recurrent kernel ----------------
#define HROW 136  // padded row stride in halfs

__global__ __launch_bounds__(512, 1) void lstm_mfma(
    const __half* __restrict__ zph, const _Float16* __restrict__ wp,
    const float* __restrict__ b_is, const float* __restrict__ b_ss,
    unsigned long long* __restrict__ hx,  // [TT][8][4][64], sentinel-filled
    float* __restrict__ out) {
  const int blk = blockIdx.x;  // 0..31
  const int rgr = blk >> 2;    // row group 0..7 (rows 8*rgr .. +7)
  const int bg = blk & 3;      // batch group 0..3 (b = 2*bg, 2*bg+1)
  const int R0 = rgr * 8;
  const int tid = threadIdx.x;
  const int wv = tid >> 6;  // wave 0..7
  const int L = tid & 63;
  const int quad = L >> 4;
  const int l15 = L & 15;
  const int rl = l15 >> 1;  // cell row-local 0..7
  const int bl = l15 & 1;   // cell batch-local 0..1
  const int b = bg * 2 + bl;
  const int r = R0 + rl;
  const int uq0 = 16 * wv + quad * 4;     // D-side unit base (+reg)
  const int zoff = (4 * wv + quad) * 16;  // zp contiguous 16-half group

  // double-buffered: slot s holds row R0-1+s (s=0..8), per b-local
  __shared__ _Float16 h_lds[2][9 * 2 * HROW];
  for (int i = tid; i < (2 * 9 * 2 * HROW) / 2; i += 512)
    ((unsigned*)h_lds)[i] = 0u;

  // ---- weights as A-fragments, loaded once ----
  v8h wfrag[4][8];
  {
    const v8h* wp8 = (const v8h*)wp;
#pragma unroll
    for (int g = 0; g < 4; g++)
#pragma unroll
      for (int kt = 0; kt < 8; kt++)
        wfrag[g][kt] = wp8[((size_t)((8 * g + wv) * 8 + kt)) * 64 + L];
  }

  float bsum[4][4];
#pragma unroll
  for (int g = 0; g < 4; g++)
#pragma unroll
    for (int rg2 = 0; rg2 < 4; rg2++) {
      int O = g * 128 + uq0 + rg2;
      bsum[g][rg2] = b_is[O] + b_ss[O];
    }

  float c[4] = {0.f, 0.f, 0.f, 0.f};
  float4 outb[4];  // shift-window out buffer (w-3..w per cell)
#pragma unroll
  for (int i = 0; i < 4; i++) outb[i] = make_float4(0.f, 0.f, 0.f, 0.f);

  const int ebl = L >> 5;       // boundary consumer: b-local
  const int eu = (L & 31) * 4;  // boundary consumer: unit base
  const int exp_idx = bl * 32 + 4 * wv + quad;  // producer slot (l15>=14)

  const bool is_cons = (wv == 0) && (rgr > 0);

  // ---- zp for t=0 (contiguous 32B: h[g*4+rg2]) ----
  union ZU {
    uint4 q[2];
    __half h[16];
  } zu;
  zu.q[0] = (uint4){0u, 0u, 0u, 0u};
  zu.q[1] = (uint4){0u, 0u, 0u, 0u};
  if (r == 0) {
    const uint4* p = (const uint4*)(zph + ((size_t)b * HH * WW) * 512 + zoff);
    zu.q[0] = p[0];
    zu.q[1] = p[1];
  }

  // ---- boundary pipeline: pend = load of hx[t] (validated at end of t) ----
  unsigned long long pend = 0ull;
  if (is_cons) {
    pend = __hip_atomic_load(&hx[(((size_t)0 * 8 + (rgr - 1)) * 4 + bg) * 64 + L],
                             __ATOMIC_RELAXED, __HIP_MEMORY_SCOPE_AGENT);
  }

  __syncthreads();

  for (int t = 0; t < TT; t++) {
    const int rb = t & 1;
    const int wb = rb ^ 1;

    // ---- issue next boundary load (hx[t+1], consumed end of t+1) ----
    unsigned long long newp = 0ull;
    if (is_cons && (t + 1) < TT) {
      newp = __hip_atomic_load(
          &hx[(((size_t)(t + 1) * 8 + (rgr - 1)) * 4 + bg) * 64 + L],
          __ATOMIC_RELAXED, __HIP_MEMORY_SCOPE_AGENT);
    }

    // ---- MFMA: kt 0..3 -> rows r-1 (slot rl); kt 4..7 -> rows r (slot rl+1)
    v4f acc[4];
#pragma unroll
    for (int g = 0; g < 4; g++) acc[g] = (v4f){0.f, 0.f, 0.f, 0.f};
#pragma unroll
    for (int kt = 0; kt < 8; kt++) {
      const int slot = (kt < 4) ? rl : (rl + 1);
      v8h bf = *(const v8h*)&h_lds[rb][(slot * 2 + bl) * HROW +
                                       (kt & 3) * 32 + quad * 8];
#pragma unroll
      for (int g = 0; g < 4; g++)
        acc[g] = __builtin_amdgcn_mfma_f32_16x16x32_f16(wfrag[g][kt], bf,
                                                        acc[g], 0, 0, 0);
    }

    // ---- gates ----
    const int w = t - r;
    const bool inband = (w >= 0) && (w < WW);
    float hv[4];
#pragma unroll
    for (int rg2 = 0; rg2 < 4; rg2++) {
      float z0 = acc[0][rg2] + bsum[0][rg2] + __half2float(zu.h[0 * 4 + rg2]);
      float z1 = acc[1][rg2] + bsum[1][rg2] + __half2float(zu.h[1 * 4 + rg2]);
      float z2 = acc[2][rg2] + bsum[2][rg2] + __half2float(zu.h[2 * 4 + rg2]);
      float z3 = acc[3][rg2] + bsum[3][rg2] + __half2float(zu.h[3 * 4 + rg2]);
      float iv = fsig(z0);
      float fv = fsig(z1);
      float ov = fsig(z2);
      float gv = ftanh_(z3);
      c[rg2] = fv * c[rg2] + iv * gv;
      hv[rg2] = ov * ftanh_(c[rg2]);
    }

    // ---- h(t) -> wb slots 1..8 (LDS, 8B per lane) ----
    {
      __half2 lo = __floats2half2_rn(hv[0], hv[1]);
      __half2 hi = __floats2half2_rn(hv[2], hv[3]);
      uint2 pk;
      pk.x = *(unsigned*)&lo;
      pk.y = *(unsigned*)&hi;
      *(uint2*)&h_lds[wb][((rl + 1) * 2 + bl) * HROW + uq0] = pk;
    }

    // ---- export h(t)[R0+7]: fire-and-forget (data == flag, no drain) ----
    if (rgr < 7 && l15 >= 14) {
      __half2 lo = __floats2half2_rn(hv[0], hv[1]);
      __half2 hi = __floats2half2_rn(hv[2], hv[3]);
      unsigned long long pk =
          ((unsigned long long)*(unsigned*)&hi << 32) | *(unsigned*)&lo;
      __hip_atomic_store(&hx[(((size_t)t * 8 + rgr) * 4 + bg) * 64 + exp_idx],
                         pk, __ATOMIC_RELAXED, __HIP_MEMORY_SCOPE_AGENT);
    }

    // ---- out shift-window; coalesced 16B flush every 4 steps per cell ----
#pragma unroll
    for (int rg2 = 0; rg2 < 4; rg2++) {
      outb[rg2].x = outb[rg2].y;
      outb[rg2].y = outb[rg2].z;
      outb[rg2].z = outb[rg2].w;
      outb[rg2].w = hv[rg2];
    }
    if (inband && (w & 3) == 3) {
      float* op_ = out + (((size_t)b * HID + uq0) * HH + r) * WW + (w - 3);
#pragma unroll
      for (int rg2 = 0; rg2 < 4; rg2++) {
        *(float4*)(op_ + (size_t)rg2 * (HH * WW)) = outb[rg2];
      }
    }

    // ---- zp prefetch for t+1 (contiguous 32B) ----
    {
      const int wn = t + 1 - r;
      if (wn >= 0 && wn < WW) {
        const uint4* p =
            (const uint4*)(zph + (((size_t)b * HH + r) * WW + wn) * 512 + zoff);
        zu.q[0] = p[0];
        zu.q[1] = p[1];
      } else {
        zu.q[0] = (uint4){0u, 0u, 0u, 0u};
        zu.q[1] = (uint4){0u, 0u, 0u, 0u};
      }
    }

    // ---- validate pend (hx[t] = h(t)[R0-1]), write to wb slot 0 ----
    if (is_cons) {
      const unsigned long long* addr =
          &hx[(((size_t)t * 8 + (rgr - 1)) * 4 + bg) * 64 + L];
      while (__ballot(pend == SENT64) != 0ull) {
        __builtin_amdgcn_s_sleep(1);
        pend = __hip_atomic_load(addr, __ATOMIC_RELAXED,
                                 __HIP_MEMORY_SCOPE_AGENT);
      }
      *(unsigned long long*)&h_lds[wb][(0 * 2 + ebl) * HROW + eu] = pend;
      pend = newp;
    }

    __syncthreads();  // wb complete; rb free for rewrite next step
  }
}

// ================= round-1 fallback path (proven correct) =================
__global__ __launch_bounds__(256) void transpose_x(const float* __restrict__ x,
                                                   float* __restrict__ xT) {
  int b = blockIdx.x >> 6;
  int r = blockIdx.x & 63;
  __shared__ float tile[32][65];
  for (int cc = 0; cc < 4; cc++) {
    int cl = threadIdx.x >> 6;
    int w = threadIdx.x & 63;
#pragma unroll
    for (int k = 0; k < 8; k++) {
      int c_loc = k * 4 + cl;
      int c = cc * 32 + c_loc;
      tile[c_loc][w] = x[(((size_t)b * 128 + c) * HH + r) * WW + w];
    }
    __syncthreads();
    int cs = threadIdx.x & 31;
    int wp = threadIdx.x >> 5;
#pragma unroll
    for (int k = 0; k < 8; k++) {
      int w2 = wp * 8 + k;
      xT[(((size_t)b * HH + r) * WW + w2) * 128 + cc * 32 + cs] = tile[cs][w2];
    }
    __syncthreads();
  }
}

__global__ __launch_bounds__(256) void step_kernel(
    const float* __restrict__ x, const float* __restrict__ xT, int use_xT,
    const float* __restrict__ w_is, const float* __restrict__ b_is,
    const float* __restrict__ w_ss, const float* __restrict__ b_ss,
    const float* __restrict__ h_prev, float* __restrict__ h_next,
    float* __restrict__ c_state, float* __restrict__ out, int t) {
  const int rg = blockIdx.x;
  const int q = blockIdx.y;
  const int r0 = rg * 2;
  const int tid = threadIdx.x;
  const int o_loc = tid & 63;
  const int k4 = tid >> 6;
  const int g_ = o_loc >> 4;
  const int u_ = o_loc & 15;
  const int O = g_ * 128 + q * 16 + u_;
  const int i0 = k4 * 32;

  __shared__ __align__(16) float h_in[3][BB][HID];
  __shared__ float zred[16][4][65];

  for (int idx = tid; idx < 3 * BB * HID; idx += 256) {
    int row_sel = idx >> 10;
    int rem = idx & 1023;
    int b = rem >> 7;
    int u = rem & 127;
    int rr = r0 - 1 + row_sel;
    h_in[row_sel][b][u] = (rr >= 0) ? h_prev[((size_t)b * HH + rr) * HID + u] : 0.0f;
  }

  float wr0[32], wr1[32], wz[32];
  {
    const float4* wss4 = (const float4*)(w_ss + ((size_t)O * 128 + i0) * 2);
#pragma unroll
    for (int j = 0; j < 16; j++) {
      float4 v = wss4[j];
      wr0[2 * j] = v.x;
      wr1[2 * j] = v.y;
      wr0[2 * j + 1] = v.z;
      wr1[2 * j + 1] = v.w;
    }
    const float4* wis4 = (const float4*)(w_is + (size_t)O * 128 + i0);
#pragma unroll
    for (int j = 0; j < 8; j++) {
      float4 v = wis4[j];
      wz[4 * j] = v.x;
      wz[4 * j + 1] = v.y;
      wz[4 * j + 2] = v.z;
      wz[4 * j + 3] = v.w;
    }
  }

  __syncthreads();

  float acc[2][BB];
#pragma unroll
  for (int rl = 0; rl < 2; rl++)
#pragma unroll
    for (int b = 0; b < BB; b++) acc[rl][b] = 0.0f;

#pragma unroll
  for (int jb = 0; jb < 8; jb++) {
    int ib = i0 + jb * 4;
#pragma unroll
    for (int b = 0; b < BB; b++) {
      const float4 hm4 = *(const float4*)&h_in[0][b][ib];
      const float4 hc4 = *(const float4*)&h_in[1][b][ib];
      const float4 hp4 = *(const float4*)&h_in[2][b][ib];
      const float* hm = (const float*)&hm4;
      const float* hc = (const float*)&hc4;
      const float* hq = (const float*)&hp4;
#pragma unroll
      for (int jj = 0; jj < 4; jj++) {
        float w0v = wr0[jb * 4 + jj];
        float w1v = wr1[jb * 4 + jj];
        acc[0][b] += w0v * hm[jj] + w1v * hc[jj];
        acc[1][b] += w0v * hc[jj] + w1v * hq[jj];
      }
    }
  }

#pragma unroll
  for (int rl = 0; rl < 2; rl++) {
    int rr = r0 + rl;
    int wcol = t - rr;
    if (wcol >= 0 && wcol < WW) {
      if (use_xT) {
        for (int b = 0; b < BB; b++) {
          const float4* xp =
              (const float4*)(xT + (((size_t)b * HH + rr) * WW + wcol) * 128 + i0);
#pragma unroll
          for (int j = 0; j < 8; j++) {
            float4 v = xp[j];
            acc[rl][b] += wz[4 * j] * v.x + wz[4 * j + 1] * v.y +
                          wz[4 * j + 2] * v.z + wz[4 * j + 3] * v.w;
          }
        }
      } else {
        for (int b = 0; b < BB; b++) {
          const float* xb = x + (((size_t)b * 128 + i0) * HH + rr) * WW + wcol;
#pragma unroll
          for (int j = 0; j < 32; j++) {
            acc[rl][b] += wz[j] * xb[(size_t)j * HH * WW];
          }
        }
      }
    }
  }

#pragma unroll
  for (int rl = 0; rl < 2; rl++)
#pragma unroll
    for (int b = 0; b < BB; b++) zred[rl * 8 + b][k4][o_loc] = acc[rl][b];
  __syncthreads();

  {
    int u = tid >> 4;
    int cell = tid & 15;
    int rl = cell >> 3;
    int b = cell & 7;
    int rr = r0 + rl;
    float z[4];
#pragma unroll
    for (int gg = 0; gg < 4; gg++) {
      int ol = gg * 16 + u;
      float s = zred[cell][0][ol] + zred[cell][1][ol] + zred[cell][2][ol] +
                zred[cell][3][ol];
      int Og = gg * 128 + q * 16 + u;
      z[gg] = s + b_is[Og] + b_ss[Og];
    }
    float iv = 1.0f / (1.0f + expf(-z[0]));
    float fv = 1.0f / (1.0f + expf(-z[1]));
    float ov = 1.0f / (1.0f + expf(-z[2]));
    float gv = tanhf(z[3]);
    int U = q * 16 + u;
    size_t sidx = ((size_t)b * HH + rr) * HID + U;
    float cv = c_state[sidx];
    float cn = fv * cv + iv * gv;
    c_state[sidx] = cn;
    float hn = ov * tanhf(cn);
    h_next[sidx] = hn;
    int wcol = t - rr;
    if (wcol >= 0 && wcol < WW) {
      out[(((size_t)b * HID + U) * HH + rr) * WW + wcol] = hn;
    }
  }
}

extern "C" void kernel_launch(void* const* d_in, const int* in_sizes, int n_in,
                              void* d_out, int out_size, void* d_ws,
                              size_t ws_size, hipStream_t stream) {
  const float* x = (const float*)d_in[0];
  const float* w_is = (const float*)d_in[1];
  const float* b_is = (const float*)d_in[2];
  const float* w_ss = (const float*)d_in[3];
  const float* b_ss = (const float*)d_in[4];
  float* outp = (float*)d_out;

  const size_t zph_bytes = (size_t)BB * HH * WW * 512 * 2;  // 32 MiB
  const size_t wp_bytes = (size_t)512 * 256 * 2;            // 256 KiB
  const size_t wisa_bytes = (size_t)512 * 128 * 2;          // 128 KiB
  const size_t hx_bytes = (size_t)TT * 8 * 4 * 64 * 8;      // ~2.03 MiB
  const size_t need = zph_bytes + wp_bytes + wisa_bytes + hx_bytes;

  char* ws = (char*)d_ws;
  if (ws_size >= need) {
    __half* zph = (__half*)ws;
    _Float16* wpp = (_Float16*)(ws + zph_bytes);
    _Float16* wisa = (_Float16*)(ws + zph_bytes + wp_bytes);
    unsigned long long* hx =
        (unsigned long long*)(ws + zph_bytes + wp_bytes + wisa_bytes);

    // prep_all covers 131072 + 65536 + 260096 = 456704 items -> 1784 blocks
    prep_all<<<dim3(1784), 256, 0, stream>>>(w_ss, w_is, wpp, wisa, hx);
    zpre_mfma<<<dim3(BB * HH), 256, 0, stream>>>(x, wisa, zph);
    lstm_mfma<<<dim3(32), 512, 0, stream>>>(zph, wpp, b_is, b_ss, hx, outp);
  } else {
    // -------- round-1 fallback --------
    const size_t xT_elems = (size_t)BB * HH * WW * 128;
    const size_t st_elems = (size_t)BB * HH * HID;
    const size_t need_xT = (xT_elems + 3 * st_elems) * sizeof(float);
    float* wsf = (float*)d_ws;
    float* xT = nullptr;
    float* st;
    int use_xT = 0;
    if (ws_size >= need_xT) {
      use_xT = 1;
      xT = wsf;
      st = wsf + xT_elems;
    } else {
      st = wsf;
    }
    float* h0 = st;
    float* h1 = st + st_elems;
    float* cb = st + 2 * st_elems;
    hipMemsetAsync(st, 0, 3 * st_elems * sizeof(float), stream);
    if (use_xT) transpose_x<<<dim3(BB * HH), 256, 0, stream>>>(x, xT);
    for (int t = 0; t < TT; t++) {
      float* hp = (t & 1) ? h1 : h0;
      float* hn = (t & 1) ? h0 : h1;
      step_kernel<<<dim3(32, 8), 256, 0, stream>>>(x, xT, use_xT, w_is, b_is,
                                                   w_ss, b_ss, hp, hn, cb, outp,
                                                   t);
    }
  }
}